// Round 13
// baseline (8145.470 us; speedup 1.0000x reference)
//
#include <hip/hip_runtime.h>

namespace {

constexpr int kT = 256;

typedef float f2 __attribute__((ext_vector_type(2)));
typedef float f4 __attribute__((ext_vector_type(4)));

__device__ __forceinline__ float fast_tanh(float x) {
    float e = __expf(2.0f * x);
    return 1.0f - 2.0f * __builtin_amdgcn_rcpf(e + 1.0f);
}

__device__ __forceinline__ float dpp_xor1(float x) {
    return __builtin_bit_cast(float, __builtin_amdgcn_update_dpp(
        0, __builtin_bit_cast(int, x), 0xB1, 0xF, 0xF, true)); // quad [1,0,3,2]
}
__device__ __forceinline__ float dpp_xor2(float x) {
    return __builtin_bit_cast(float, __builtin_amdgcn_update_dpp(
        0, __builtin_bit_cast(int, x), 0x4E, 0xF, 0xF, true)); // quad [2,3,0,1]
}
__device__ __forceinline__ float dpp_ror8(float x) {           // lane ^ 8 within row16
    return __builtin_bit_cast(float, __builtin_amdgcn_update_dpp(
        0, __builtin_bit_cast(int, x), 0x128, 0xF, 0xF, true)); // row_ror:8
}
template <int PAT>
__device__ __forceinline__ float swz(float x) {
    return __builtin_bit_cast(float,
        __builtin_amdgcn_ds_swizzle(__builtin_bit_cast(int, x), PAT));
}
__device__ __forceinline__ float read_lane(float x, int lane) {
    return __builtin_bit_cast(float,
        __builtin_amdgcn_readlane(__builtin_bit_cast(int, x), lane));
}

// h storage, k-major with rows fast: element (k, r) at float offset
// 4*k + 4*(k>>4) + r  -- INJECTIVE (r12's (k>>3)&7 pad wrapped mod 8 and
// aliased k=57..63 onto k=64..70 -> absmax 1.94 correctness failure; this
// is the r8/r9-verified pad). One ds_read_b128 at k yields h[k][r0..r3],
// so the k-sum accumulates serially in-register -> NO k-parity horizontal
// adds (f2 accumulator components are row-pairs, distinct outputs).
// Banks: GEMM b128 read bases 32*kc + 4*(kc>>1) -> quad 4*(kc>>1) mod 32,
// 8 quads x 2 lanes = 2-way = free; GEMM writes 2-way; the once-per-dyn
// input-write/output-reads are 8-way single-b32 ops (negligible).
//
// STRUCTURAL LEDGER (hard-won):
//  * 512-thread block = 8 waves = 2 waves/SIMD ALWAYS -> hard 128 VGPR cap.
//    Safe register shapes (no spill): f2 weight tuples (48), f2/even-aligned
//    accumulators, <=2 b128 loads in flight per iteration. Spilling shapes
//    (r1/r2/r5/r9/r10, 128-pin + 59-70 GB FETCH): 96-scalar weights, f4-quad
//    weights or accumulators, 16-deep b128 chains (sched_barrier didn't fix).
//  * Occupancy is NOT a lever: a 2nd block/CU never co-resides (r7).
//    Keep 256 blocks x 512 threads, 4 rows/block.
//  * Butterfly: uniform (XOR-permuted jj) stages first at high width,
//    keyed r stages last (r11: 54->36 VALU/layer).
//  * LDS index maps MUST be checked injective before landing (r12 lesson).
__device__ __forceinline__ int haddr(int k, int r) {
    return 4 * k + 4 * (k >> 4) + r;
}

__global__ __launch_bounds__(512, 1) void hybrid_ode_kernel(
    const float* __restrict__ y0,
    const float* __restrict__ t_span,
    const float* __restrict__ meal,
    const float* __restrict__ tvns,
    const float* __restrict__ W_in, const float* __restrict__ b_in,
    const float* __restrict__ W_h,  const float* __restrict__ b_h,
    const float* __restrict__ W_out,const float* __restrict__ b_out,
    float* __restrict__ out)
{
    const int tid = threadIdx.x;
    const int w   = tid >> 6;          // wave 0..7
    const int l   = tid & 63;
    const int jgl = l >> 4;            // 0..3 j-group within wave
    const int kc  = l & 15;            // k-chunk (8 k's)
    const int kch = kc >> 2;           // high 2 bits of kc (j-XOR key)
    const int jg  = w * 4 + jgl;       // 0..31
    const int jb  = jg * 4;            // thread's 4 j's: jb..jb+3 (XOR-permuted)
    const int rw  = w & 3;             // batch row this wave carries
    const int row = blockIdx.x * 4 + rw;

    // produced output slot after reduce-scatter (same mapping as r11)
    const int r_p = kc & 3;
    const int j_p = jb + kch;
    const int waddr = haddr(j_p, r_p);
    const bool pb0 = (kc & 1) != 0;
    const bool pb1 = (kc & 2) != 0;

    __shared__ __align__(16) float hp0[544];
    __shared__ __align__(16) float hp1[544];

    // ---- one-time weight staging into registers (proven f2 shape).
    // wgt[ll][ka][jj]: .x = W_h[ll][8kc+2ka][col], .y = W_h[ll][8kc+2ka+1][col],
    // col = jb + (jj ^ kch). The j-XOR makes the jj butterfly stages uniform.
    f2 wgt[3][4][4];
    #pragma unroll
    for (int ll = 0; ll < 3; ++ll)
        #pragma unroll
        for (int ka = 0; ka < 4; ++ka)
            #pragma unroll
            for (int jj = 0; jj < 4; ++jj) {
                const float* p = W_h + (size_t)(ll * 128 + 8 * kc + 2 * ka) * 128
                               + jb + (jj ^ kch);
                f2 v; v.x = p[0]; v.y = p[128];
                wgt[ll][ka][jj] = v;
            }

    // Input layer register-direct: wave w covers row rw = w&3, cols
    // j2 = l + 64*(w>>2). x-vector is wave-uniform in registers; the two
    // y3 terms (k=4, k=7) fold into one staged weight.
    const int j2 = l + 64 * (w >> 2);
    const int waddr2 = haddr(j2, rw);
    float win[8];
    win[0] = W_in[0 * 128 + j2];                         // t
    win[1] = W_in[1 * 128 + j2];                         // y0
    win[2] = W_in[2 * 128 + j2];                         // y1
    win[3] = W_in[3 * 128 + j2];                         // y2
    win[4] = W_in[4 * 128 + j2] + W_in[7 * 128 + j2];    // y3 (+ glp1=y3)
    win[5] = W_in[5 * 128 + j2];                         // y4
    win[6] = W_in[6 * 128 + j2];                         // y5
    win[7] = W_in[8 * 128 + j2];                         // v
    const float bin = b_in[j2];

    float bh[3];
    #pragma unroll
    for (int ll = 0; ll < 3; ++ll) bh[ll] = b_h[ll * 128 + j_p];

    // output layer: XOR-permuted weights for a 3-bit reduce-scatter (s lands at l&7)
    const int s8 = l & 7;
    float wo0p[8], wo1p[8], bo[6];
    #pragma unroll
    for (int p = 0; p < 8; ++p) {
        const int q = p ^ s8;
        wo0p[p] = (q < 6) ? W_out[l * 6 + q] : 0.0f;
        wo1p[p] = (q < 6) ? W_out[(l + 64) * 6 + q] : 0.0f;
    }
    #pragma unroll
    for (int s = 0; s < 6; ++s) bo[s] = b_out[s];
    const int oaddrA = haddr(l, 0);        // + rw at use
    const int oaddrB = haddr(l + 64, 0);

    float y[6];
    #pragma unroll
    for (int s = 0; s < 6; ++s) y[s] = y0[row * 6 + s];

    if (w < 4 && l == 0) {
        #pragma unroll
        for (int s = 0; s < 6; ++s) out[(size_t)row * kT * 6 + s] = y[s];
    }

    const float* mrow = meal + (size_t)row * kT;
    const float* vrow = tvns + (size_t)row * kT;

    auto dyn = [&](float t, const float* yc, float m, float v, float* d) {
        // ---- input layer 9->128, register-direct. Prior hp0 readers
        // (layer ll=2) are ordered by the previous dyn's post-L3 barrier.
        {
            float s = bin + t * win[0];
            s += yc[0] * win[1] + yc[1] * win[2] + yc[2] * win[3];
            s += yc[3] * win[4] + yc[4] * win[5] + yc[5] * win[6];
            s += v * win[7];
            hp0[waddr2] = fast_tanh(s);
        }
        __syncthreads();

        // ---- 3 hidden layers 128->128
        #pragma unroll
        for (int ll = 0; ll < 3; ++ll) {
            const float* rb = (ll & 1) ? hp1 : hp0;
            float*       wb = (ll & 1) ? hp0 : hp1;

            // 8x ds_read_b128 (2 per ka, r6-proven shape); acc components
            // are ROW pairs -> k accumulates serially, no horizontal add.
            // Base: k0 = 8*kc, haddr(k0,0) = 32*kc + 4*(kc>>1); k>>4 is
            // constant over the thread's 8 k's so stepping is +4 words/k.
            const float* hb = rb + 32 * kc + 4 * (kc >> 1);
            f2 acc[4][2];   // [jj][rp]: rp0 = rows (0,1), rp1 = rows (2,3)
            #pragma unroll
            for (int ka = 0; ka < 4; ++ka) {
                f4 qe = *(const f4*)(hb + 8 * ka);       // k = 8kc+2ka
                f4 qo = *(const f4*)(hb + 8 * ka + 4);   // k = 8kc+2ka+1
                f2 e01 = __builtin_shufflevector(qe, qe, 0, 1);
                f2 e23 = __builtin_shufflevector(qe, qe, 2, 3);
                f2 o01 = __builtin_shufflevector(qo, qo, 0, 1);
                f2 o23 = __builtin_shufflevector(qo, qo, 2, 3);
                #pragma unroll
                for (int jj = 0; jj < 4; ++jj) {
                    const f2 wv = wgt[ll][ka][jj];
                    if (ka == 0) {
                        acc[jj][0] = e01 * wv.x;
                        acc[jj][1] = e23 * wv.x;
                    } else {
                        acc[jj][0] = e01 * wv.x + acc[jj][0];
                        acc[jj][1] = e23 * wv.x + acc[jj][1];
                    }
                    acc[jj][0] = o01 * wv.y + acc[jj][0];
                    acc[jj][1] = o23 * wv.y + acc[jj][1];
                }
            }

            // 4-stage reduce-scatter over the 16 kc lanes, uniform-first.
            // scalar view a[jj][r] = acc[jj][r>>1][r&1].
            // stage kc-bit3 <-> jj-bit1 (uniform, dpp ror8, fully fused):
            // keep jj in {0,1}, receive partner's {2,3}.
            float B0[4], B1[4];
            #pragma unroll
            for (int r = 0; r < 4; ++r) {
                B0[r] = acc[0][r >> 1][r & 1] + dpp_ror8(acc[2][r >> 1][r & 1]);
                B1[r] = acc[1][r >> 1][r & 1] + dpp_ror8(acc[3][r >> 1][r & 1]);
            }
            // stage kc-bit2 <-> jj-bit0 (uniform, swz xor4)
            float C[4];
            #pragma unroll
            for (int r = 0; r < 4; ++r)
                C[r] = B0[r] + swz<0x101F>(B1[r]);
            // stage kc-bit0 <-> r-bit0 (keyed keep/give)
            float D[2];
            #pragma unroll
            for (int i = 0; i < 2; ++i) {
                const float keep = pb0 ? C[2*i+1] : C[2*i];
                const float give = pb0 ? C[2*i]   : C[2*i+1];
                D[i] = keep + dpp_xor1(give);
            }
            // stage kc-bit1 <-> r-bit1 (keyed keep/give)
            const float keep = pb1 ? D[1] : D[0];
            const float give = pb1 ? D[0] : D[1];
            const float S = keep + dpp_xor2(give);

            wb[waddr] = fast_tanh(S + bh[ll]);
            __syncthreads();
        }

        // ---- output layer 128->6 for this wave's row; h3 lives in hp1.
        const float hA = hp1[oaddrA + rw];
        const float hB = hp1[oaddrB + rw];
        float P[8];
        #pragma unroll
        for (int p = 0; p < 8; ++p) P[p] = hA * wo0p[p] + hB * wo1p[p];
        float Q[4];
        #pragma unroll
        for (int i = 0; i < 4; ++i) Q[i] = P[2*i] + dpp_xor1(P[2*i+1]);
        const float R0 = Q[0] + dpp_xor2(Q[1]);
        const float R1 = Q[2] + dpp_xor2(Q[3]);
        float S = R0 + swz<0x101F>(R1);   // xor4
        S += dpp_ror8(S);                 // xor8
        S += swz<0x401F>(S);              // xor16
        S += __shfl_xor(S, 32);           // xor32

        const float p0 = read_lane(S, 0);
        const float p1 = read_lane(S, 1);
        const float p2 = read_lane(S, 2);
        const float p3 = read_lane(S, 3);
        const float p4 = read_lane(S, 4);
        const float p5 = read_lane(S, 5);

        const float G = yc[0], I = yc[1], N = yc[2], L = yc[3], GE = yc[4], F = yc[5];
        d[0] = -0.01f*I*G + 0.05f*GE                                    + p0 + bo[0];
        d[1] = (G/(100.0f+G))*(1.0f + 2.0f*L/(5.0f+L)) - 0.1f*I         + p1 + bo[1];
        d[2] = -0.05f*N                                                 + p2 + bo[2];
        d[3] = 0.05f*GE - 0.2f*L                                        + p3 + bo[3];
        d[4] = m - 0.05f*GE                                             + p4 + bo[4];
        d[5] = -0.01f*I*F                                               + p5 + bo[5];
    };

    for (int i = 0; i < kT - 1; ++i) {
        const float t0 = t_span[i], t1 = t_span[i + 1];
        const float dt = t1 - t0;
        const float m0 = mrow[i], m1 = mrow[i + 1];
        const float v0 = vrow[i], v1 = vrow[i + 1];
        const float tm = t0 + 0.5f * dt;
        const float mm = 0.5f * (m0 + m1), vm = 0.5f * (v0 + v1);

        float d[6], ksum[6], yc[6];

        dyn(t0, y, m0, v0, d);
        #pragma unroll
        for (int s = 0; s < 6; ++s) { ksum[s] = d[s]; yc[s] = y[s] + 0.5f * dt * d[s]; }
        dyn(tm, yc, mm, vm, d);
        #pragma unroll
        for (int s = 0; s < 6; ++s) { ksum[s] += 2.0f * d[s]; yc[s] = y[s] + 0.5f * dt * d[s]; }
        dyn(tm, yc, mm, vm, d);
        #pragma unroll
        for (int s = 0; s < 6; ++s) { ksum[s] += 2.0f * d[s]; yc[s] = y[s] + dt * d[s]; }
        dyn(t1, yc, m1, v1, d);
        #pragma unroll
        for (int s = 0; s < 6; ++s) {
            ksum[s] += d[s];
            y[s] += (dt * (1.0f / 6.0f)) * ksum[s];
        }

        if (w < 4 && l == 0) {
            #pragma unroll
            for (int s = 0; s < 6; ++s)
                out[((size_t)row * kT + (i + 1)) * 6 + s] = y[s];
        }
    }
}

} // namespace

extern "C" void kernel_launch(void* const* d_in, const int* in_sizes, int n_in,
                              void* d_out, int out_size, void* d_ws, size_t ws_size,
                              hipStream_t stream) {
    const float* y0     = (const float*)d_in[0];
    const float* t_span = (const float*)d_in[1];
    const float* meal   = (const float*)d_in[2];
    const float* tvns   = (const float*)d_in[3];
    const float* W_in   = (const float*)d_in[4];
    const float* b_in   = (const float*)d_in[5];
    const float* W_h    = (const float*)d_in[6];
    const float* b_h    = (const float*)d_in[7];
    const float* W_out  = (const float*)d_in[8];
    const float* b_out  = (const float*)d_in[9];
    float* out          = (float*)d_out;

    hipLaunchKernelGGL(hybrid_ode_kernel, dim3(256), dim3(512), 0, stream,
                       y0, t_span, meal, tvns,
                       W_in, b_in, W_h, b_h, W_out, b_out, out);
}

// Round 14
// 2326.368 us; speedup vs baseline: 3.5014x; 3.5014x over previous
//
#include <hip/hip_runtime.h>

namespace {

constexpr int kT = 256;

typedef float f2 __attribute__((ext_vector_type(2)));
typedef float f4 __attribute__((ext_vector_type(4)));

__device__ __forceinline__ float fast_tanh(float x) {
    float e = __expf(2.0f * x);
    return 1.0f - 2.0f * __builtin_amdgcn_rcpf(e + 1.0f);
}

__device__ __forceinline__ float dpp_xor1(float x) {
    return __builtin_bit_cast(float, __builtin_amdgcn_update_dpp(
        0, __builtin_bit_cast(int, x), 0xB1, 0xF, 0xF, true)); // quad [1,0,3,2]
}
__device__ __forceinline__ float dpp_xor2(float x) {
    return __builtin_bit_cast(float, __builtin_amdgcn_update_dpp(
        0, __builtin_bit_cast(int, x), 0x4E, 0xF, 0xF, true)); // quad [2,3,0,1]
}
__device__ __forceinline__ float dpp_ror8(float x) {           // lane ^ 8 within row16
    return __builtin_bit_cast(float, __builtin_amdgcn_update_dpp(
        0, __builtin_bit_cast(int, x), 0x128, 0xF, 0xF, true)); // row_ror:8
}
template <int PAT>
__device__ __forceinline__ float swz(float x) {
    return __builtin_bit_cast(float,
        __builtin_amdgcn_ds_swizzle(__builtin_bit_cast(int, x), PAT));
}
__device__ __forceinline__ float read_lane(float x, int lane) {
    return __builtin_bit_cast(float,
        __builtin_amdgcn_readlane(__builtin_bit_cast(int, x), lane));
}

// h storage: element (k2,r,b) at float offset 8*k2 + 4*(k2>>2) + 2*r + b,
// where k2 = k>>1, b = k&1. f2 pair (k even, k odd) is contiguous; the
// pad 4*(k2>>2) spreads kc-chunks across banks (<=2-way everywhere).
//
// STRUCTURAL LEDGER (hard-won; r = round):
//  * 512-thread block = 8 waves = 2 waves/SIMD ALWAYS -> hard 128 VGPR cap.
//    THIS f2-k-parity core is the ONLY register-stable GEMM shape found
//    (112 VGPR, no spill). TERMINALLY DEAD families (all 128-pin + GB-scale
//    scratch FETCH): f4-quad weights/accs (r1/r2/r5), k-major row-fast
//    layout with ANY acc shape -- f4 (r9), chunked+sched_barrier (r10),
//    f2 row-pair acc (r13, 18 GB FETCH, VALUBusy 16%). Mechanism: k-serial
//    accumulation chains force load/extract hoisting; transient pressure
//    at the cap evicts the 96-reg wgt array. k-parity packing gives two
//    independent FMA chains per jj -> no hoisting -> fits.
//  * Occupancy is NOT a lever: a 2nd block/CU never co-resides (r7: 512
//    blocks ran as 2 sequential passes). Keep 256 blocks x 512 threads.
//  * Butterfly: uniform (XOR-permuted jj) stages FIRST at high width,
//    keyed r stages last (r11: 54->36 VALU/layer, -200 us).
//  * LDS index maps MUST be checked injective before landing (r12 lesson:
//    a mod-wrapping pad aliased k-groups -> absmax 1.94).
//  * Horizontal k-parity adds (48/dyn) are the accepted price of the
//    register-stable shape; removing them (k-major) costs 3.5x in spill.
__device__ __forceinline__ int haddr(int j, int r) {
    return 8 * (j >> 1) + 4 * (j >> 3) + 2 * r + (j & 1);
}

__global__ __launch_bounds__(512, 1) void hybrid_ode_kernel(
    const float* __restrict__ y0,
    const float* __restrict__ t_span,
    const float* __restrict__ meal,
    const float* __restrict__ tvns,
    const float* __restrict__ W_in, const float* __restrict__ b_in,
    const float* __restrict__ W_h,  const float* __restrict__ b_h,
    const float* __restrict__ W_out,const float* __restrict__ b_out,
    float* __restrict__ out)
{
    const int tid = threadIdx.x;
    const int w   = tid >> 6;          // wave 0..7
    const int l   = tid & 63;
    const int jgl = l >> 4;            // 0..3 j-group within wave
    const int kc  = l & 15;            // k-chunk (8 k's)
    const int kch = kc >> 2;           // high 2 bits of kc (j-XOR key)
    const int jg  = w * 4 + jgl;       // 0..31
    const int jb  = jg * 4;            // thread's 4 j's: jb..jb+3 (XOR-permuted)
    const int rw  = w & 3;             // batch row this wave carries
    const int row = blockIdx.x * 4 + rw;

    // produced output slot after reduce-scatter
    const int r_p = kc & 3;
    const int j_p = jb + kch;
    const int waddr = haddr(j_p, r_p);
    const bool pb0 = (kc & 1) != 0;
    const bool pb1 = (kc & 2) != 0;

    __shared__ __align__(16) float hp0[576];
    __shared__ __align__(16) float hp1[576];

    // ---- one-time weight staging into registers
    // wgt[ll][ka][jj] holds column j = jb + (jj ^ kch): the j-XOR makes
    // the jj butterfly stages uniform (no keep/give selects there).
    f2 wgt[3][4][4];   // [layer][kpair kappa][jj]: k = 8kc+2*ka (+1)
    #pragma unroll
    for (int ll = 0; ll < 3; ++ll)
        #pragma unroll
        for (int ka = 0; ka < 4; ++ka)
            #pragma unroll
            for (int jj = 0; jj < 4; ++jj) {
                const float* p = W_h + (size_t)(ll * 128 + 8 * kc + 2 * ka) * 128
                               + jb + (jj ^ kch);
                f2 v; v.x = p[0]; v.y = p[128];
                wgt[ll][ka][jj] = v;
            }

    // Input layer is register-direct: waves 0..3 produce rows 0..3, cols
    // 0..63; waves 4..7 same rows, cols 64..127. x-vector is wave-uniform
    // in registers. The two y3 terms (k=4, k=7) fold into one staged weight.
    const int j2 = l + 64 * (w >> 2);
    const int waddr2 = haddr(j2, rw);
    float win[8];
    win[0] = W_in[0 * 128 + j2];                         // t
    win[1] = W_in[1 * 128 + j2];                         // y0
    win[2] = W_in[2 * 128 + j2];                         // y1
    win[3] = W_in[3 * 128 + j2];                         // y2
    win[4] = W_in[4 * 128 + j2] + W_in[7 * 128 + j2];    // y3 (+ glp1=y3)
    win[5] = W_in[5 * 128 + j2];                         // y4
    win[6] = W_in[6 * 128 + j2];                         // y5
    win[7] = W_in[8 * 128 + j2];                         // v
    const float bin = b_in[j2];

    float bh[3];
    #pragma unroll
    for (int ll = 0; ll < 3; ++ll) bh[ll] = b_h[ll * 128 + j_p];

    // output layer: XOR-permuted weights for a 3-bit reduce-scatter (s lands at l&7)
    const int s8 = l & 7;
    float wo0p[8], wo1p[8], bo[6];
    #pragma unroll
    for (int p = 0; p < 8; ++p) {
        const int q = p ^ s8;
        wo0p[p] = (q < 6) ? W_out[l * 6 + q] : 0.0f;
        wo1p[p] = (q < 6) ? W_out[(l + 64) * 6 + q] : 0.0f;
    }
    #pragma unroll
    for (int s = 0; s < 6; ++s) bo[s] = b_out[s];
    const int oaddr = 8 * (l >> 1) + 4 * (l >> 3) + (l & 1);  // + 2*rw at use

    float y[6];
    #pragma unroll
    for (int s = 0; s < 6; ++s) y[s] = y0[row * 6 + s];

    if (w < 4 && l == 0) {
        #pragma unroll
        for (int s = 0; s < 6; ++s) out[(size_t)row * kT * 6 + s] = y[s];
    }

    const float* mrow = meal + (size_t)row * kT;
    const float* vrow = tvns + (size_t)row * kT;

    auto dyn = [&](float t, const float* yc, float m, float v, float* d) {
        // ---- input layer 9->128, register-direct. Prior hp0 readers
        // (layer ll=2) are ordered by the previous dyn's post-L3 barrier.
        {
            float s = bin + t * win[0];
            s += yc[0] * win[1] + yc[1] * win[2] + yc[2] * win[3];
            s += yc[3] * win[4] + yc[4] * win[5] + yc[5] * win[6];
            s += v * win[7];
            hp0[waddr2] = fast_tanh(s);
        }
        __syncthreads();

        // ---- 3 hidden layers 128->128
        #pragma unroll
        for (int ll = 0; ll < 3; ++ll) {
            const float* rb = (ll & 1) ? hp1 : hp0;
            float*       wb = (ll & 1) ? hp0 : hp1;

            f2 acc[4][4];   // [jj][r], packed over k-parity
            #pragma unroll
            for (int ka = 0; ka < 4; ++ka) {
                const int base = 36 * kc + 8 * ka;
                f4 q0 = *(const f4*)(rb + base);
                f4 q1 = *(const f4*)(rb + base + 4);
                f2 h0 = __builtin_shufflevector(q0, q0, 0, 1);
                f2 h1 = __builtin_shufflevector(q0, q0, 2, 3);
                f2 h2 = __builtin_shufflevector(q1, q1, 0, 1);
                f2 h3 = __builtin_shufflevector(q1, q1, 2, 3);
                #pragma unroll
                for (int jj = 0; jj < 4; ++jj) {
                    const f2 wv = wgt[ll][ka][jj];
                    if (ka == 0) {
                        acc[jj][0] = h0 * wv;
                        acc[jj][1] = h1 * wv;
                        acc[jj][2] = h2 * wv;
                        acc[jj][3] = h3 * wv;
                    } else {
                        acc[jj][0] = h0 * wv + acc[jj][0];
                        acc[jj][1] = h1 * wv + acc[jj][1];
                        acc[jj][2] = h2 * wv + acc[jj][2];
                        acc[jj][3] = h3 * wv + acc[jj][3];
                    }
                }
            }

            // horizontal add over k-parity; A indexed by o = (jj<<2)|r,
            // value is column j = jb + (jj ^ kch), row r.
            float A[16];
            #pragma unroll
            for (int o = 0; o < 16; ++o)
                A[o] = acc[o >> 2][o & 3].x + acc[o >> 2][o & 3].y;

            // 4-stage reduce-scatter over the 16 kc lanes, UNIFORM-FIRST
            // order (jj stages at 16/8 elems cost 2 ops/pair; keyed r
            // stages run last at 4/2 elems): 36 VALU vs 54 keyed-first.
            // stage kc-bit2 <-> jj-bit0 (uniform, swz xor4): keep jj0=0 slot
            float B[8];    // index (jj1<<2)|r
            #pragma unroll
            for (int i = 0; i < 8; ++i)
                B[i] = A[(i & 3) | ((i >> 2) << 3)]
                     + swz<0x101F>(A[(i & 3) | ((i >> 2) << 3) | 4]);
            // stage kc-bit3 <-> jj-bit1 (uniform, ror8 = xor8 in row16)
            float C[4];    // index r
            #pragma unroll
            for (int r = 0; r < 4; ++r)
                C[r] = B[r] + dpp_ror8(B[r + 4]);
            // stage kc-bit0 <-> r-bit0 (keyed keep/give)
            float D[2];
            #pragma unroll
            for (int i = 0; i < 2; ++i) {
                const float keep = pb0 ? C[2*i+1] : C[2*i];
                const float give = pb0 ? C[2*i]   : C[2*i+1];
                D[i] = keep + dpp_xor1(give);
            }
            // stage kc-bit1 <-> r-bit1 (keyed keep/give)
            const float keep = pb1 ? D[1] : D[0];
            const float give = pb1 ? D[0] : D[1];
            const float S = keep + dpp_xor2(give);

            wb[waddr] = fast_tanh(S + bh[ll]);
            __syncthreads();
        }

        // ---- output layer 128->6 for this wave's row; h3 lives in hp1.
        // Reduce-scatter s to lane s8 (uniform, XOR'd weights), all-reduce
        // the 8-lane groups, then readlane-broadcast p[0..5] as wave scalars.
        const float hA = hp1[oaddr + 2 * rw];
        const float hB = hp1[oaddr + 2 * rw + 288];
        float P[8];
        #pragma unroll
        for (int p = 0; p < 8; ++p) P[p] = hA * wo0p[p] + hB * wo1p[p];
        float Q[4];
        #pragma unroll
        for (int i = 0; i < 4; ++i) Q[i] = P[2*i] + dpp_xor1(P[2*i+1]);
        const float R0 = Q[0] + dpp_xor2(Q[1]);
        const float R1 = Q[2] + dpp_xor2(Q[3]);
        float S = R0 + swz<0x101F>(R1);   // xor4
        S += dpp_ror8(S);                 // xor8
        S += swz<0x401F>(S);              // xor16
        S += __shfl_xor(S, 32);           // xor32

        const float p0 = read_lane(S, 0);
        const float p1 = read_lane(S, 1);
        const float p2 = read_lane(S, 2);
        const float p3 = read_lane(S, 3);
        const float p4 = read_lane(S, 4);
        const float p5 = read_lane(S, 5);

        const float G = yc[0], I = yc[1], N = yc[2], L = yc[3], GE = yc[4], F = yc[5];
        d[0] = -0.01f*I*G + 0.05f*GE                                    + p0 + bo[0];
        d[1] = (G/(100.0f+G))*(1.0f + 2.0f*L/(5.0f+L)) - 0.1f*I         + p1 + bo[1];
        d[2] = -0.05f*N                                                 + p2 + bo[2];
        d[3] = 0.05f*GE - 0.2f*L                                        + p3 + bo[3];
        d[4] = m - 0.05f*GE                                             + p4 + bo[4];
        d[5] = -0.01f*I*F                                               + p5 + bo[5];
    };

    for (int i = 0; i < kT - 1; ++i) {
        const float t0 = t_span[i], t1 = t_span[i + 1];
        const float dt = t1 - t0;
        const float m0 = mrow[i], m1 = mrow[i + 1];
        const float v0 = vrow[i], v1 = vrow[i + 1];
        const float tm = t0 + 0.5f * dt;
        const float mm = 0.5f * (m0 + m1), vm = 0.5f * (v0 + v1);

        float d[6], ksum[6], yc[6];

        dyn(t0, y, m0, v0, d);
        #pragma unroll
        for (int s = 0; s < 6; ++s) { ksum[s] = d[s]; yc[s] = y[s] + 0.5f * dt * d[s]; }
        dyn(tm, yc, mm, vm, d);
        #pragma unroll
        for (int s = 0; s < 6; ++s) { ksum[s] += 2.0f * d[s]; yc[s] = y[s] + 0.5f * dt * d[s]; }
        dyn(tm, yc, mm, vm, d);
        #pragma unroll
        for (int s = 0; s < 6; ++s) { ksum[s] += 2.0f * d[s]; yc[s] = y[s] + dt * d[s]; }
        dyn(t1, yc, m1, v1, d);
        #pragma unroll
        for (int s = 0; s < 6; ++s) {
            ksum[s] += d[s];
            y[s] += (dt * (1.0f / 6.0f)) * ksum[s];
        }

        if (w < 4 && l == 0) {
            #pragma unroll
            for (int s = 0; s < 6; ++s)
                out[((size_t)row * kT + (i + 1)) * 6 + s] = y[s];
        }
    }
}

} // namespace

extern "C" void kernel_launch(void* const* d_in, const int* in_sizes, int n_in,
                              void* d_out, int out_size, void* d_ws, size_t ws_size,
                              hipStream_t stream) {
    const float* y0     = (const float*)d_in[0];
    const float* t_span = (const float*)d_in[1];
    const float* meal   = (const float*)d_in[2];
    const float* tvns   = (const float*)d_in[3];
    const float* W_in   = (const float*)d_in[4];
    const float* b_in   = (const float*)d_in[5];
    const float* W_h    = (const float*)d_in[6];
    const float* b_h    = (const float*)d_in[7];
    const float* W_out  = (const float*)d_in[8];
    const float* b_out  = (const float*)d_in[9];
    float* out          = (float*)d_out;

    hipLaunchKernelGGL(hybrid_ode_kernel, dim3(256), dim3(512), 0, stream,
                       y0, t_span, meal, tvns,
                       W_in, b_in, W_h, b_h, W_out, b_out, out);
}

// Round 15
// 2278.552 us; speedup vs baseline: 3.5748x; 1.0210x over previous
//
#include <hip/hip_runtime.h>

namespace {

constexpr int kT = 256;

typedef float f2 __attribute__((ext_vector_type(2)));
typedef float f4 __attribute__((ext_vector_type(4)));

__device__ __forceinline__ float fast_tanh(float x) {
    float e = __expf(2.0f * x);
    return 1.0f - 2.0f * __builtin_amdgcn_rcpf(e + 1.0f);
}

__device__ __forceinline__ float dpp_xor1(float x) {
    return __builtin_bit_cast(float, __builtin_amdgcn_update_dpp(
        0, __builtin_bit_cast(int, x), 0xB1, 0xF, 0xF, true)); // quad [1,0,3,2]
}
__device__ __forceinline__ float dpp_xor2(float x) {
    return __builtin_bit_cast(float, __builtin_amdgcn_update_dpp(
        0, __builtin_bit_cast(int, x), 0x4E, 0xF, 0xF, true)); // quad [2,3,0,1]
}
__device__ __forceinline__ float dpp_ror8(float x) {           // lane ^ 8 within row16
    return __builtin_bit_cast(float, __builtin_amdgcn_update_dpp(
        0, __builtin_bit_cast(int, x), 0x128, 0xF, 0xF, true)); // row_ror:8
}
template <int PAT>
__device__ __forceinline__ float swz(float x) {
    return __builtin_bit_cast(float,
        __builtin_amdgcn_ds_swizzle(__builtin_bit_cast(int, x), PAT));
}
__device__ __forceinline__ float read_lane(float x, int lane) {
    return __builtin_bit_cast(float,
        __builtin_amdgcn_readlane(__builtin_bit_cast(int, x), lane));
}

// h storage: SLOT s of index j at float offset 8*(j>>1) + 4*(j>>3) + 2*s
// + (j&1). ROW-SLOT PERMUTATION: row r of index j is stored at slot
// s = r ^ ((j>>3)&3). Readers of index k all have kc = k>>3, so in slot
// space every lane's surviving reduce-scatter slot is slot 0 -> the two
// r-keyed butterfly stages become UNIFORM fused dpp adds (no cndmask).
// Permutation is a bijection within each 4-row group (injective; r12
// lesson) and only permutes contents within existing 8-float groups ->
// bank profile identical to r11 (<=2-way everywhere on GEMM traffic).
//
// STRUCTURAL LEDGER (hard-won; r = round):
//  * 512-thread block = 8 waves = 2 waves/SIMD ALWAYS -> hard 128 VGPR cap.
//    THIS f2-k-parity core is the ONLY register-stable GEMM shape found
//    (112 VGPR, no spill). TERMINALLY DEAD families (all 128-pin + GB-scale
//    scratch FETCH): f4-quad weights/accs (r1/r2/r5), k-major row-fast
//    layout with ANY acc shape (r9/r10/r13). Mechanism: k-serial
//    accumulation chains force load/extract hoisting; transient pressure
//    at the cap evicts the 96-reg wgt array. k-parity packing gives two
//    independent FMA chains per jj -> no hoisting -> fits.
//  * Occupancy is NOT a lever: a 2nd block/CU never co-resides (r7).
//    Keep 256 blocks x 512 threads, 4 rows/block.
//  * Butterfly: ALL stages uniform now -- jj stages via the jj^kch column
//    permutation (r3), r stages via the row-slot permutation (this round).
//    Uniform-first order at high width (r11: 54->36; now ~30 VALU/layer).
//  * Horizontal k-parity adds (48/dyn) are the accepted price of the
//    register-stable shape; removing them (k-major) costs 3.5x in spill.
__device__ __forceinline__ int haddr(int j, int s) {
    return 8 * (j >> 1) + 4 * (j >> 3) + 2 * s + (j & 1);
}

__global__ __launch_bounds__(512, 1) void hybrid_ode_kernel(
    const float* __restrict__ y0,
    const float* __restrict__ t_span,
    const float* __restrict__ meal,
    const float* __restrict__ tvns,
    const float* __restrict__ W_in, const float* __restrict__ b_in,
    const float* __restrict__ W_h,  const float* __restrict__ b_h,
    const float* __restrict__ W_out,const float* __restrict__ b_out,
    float* __restrict__ out)
{
    const int tid = threadIdx.x;
    const int w   = tid >> 6;          // wave 0..7
    const int l   = tid & 63;
    const int jgl = l >> 4;            // 0..3 j-group within wave
    const int kc  = l & 15;            // k-chunk (8 k's)
    const int kch = kc >> 2;           // high 2 bits of kc (column-XOR key)
    const int jg  = w * 4 + jgl;       // 0..31
    const int jb  = jg * 4;            // thread's 4 j's: jb..jb+3 (XOR-permuted)
    const int rw  = w & 3;             // batch row this wave carries
    const int row = blockIdx.x * 4 + rw;

    // produced output slot after reduce-scatter: row r_p of column j_p,
    // stored at the permuted slot r_p ^ ((j_p>>3)&3).
    const int r_p = kc & 3;
    const int j_p = jb + kch;
    const int waddr = haddr(j_p, r_p ^ ((j_p >> 3) & 3));

    __shared__ __align__(16) float hp0[576];
    __shared__ __align__(16) float hp1[576];

    // ---- one-time weight staging into registers
    // wgt[ll][ka][jj] holds column j = jb + (jj ^ kch): the column-XOR
    // makes the jj butterfly stages uniform.
    f2 wgt[3][4][4];   // [layer][kpair kappa][jj]: k = 8kc+2*ka (+1)
    #pragma unroll
    for (int ll = 0; ll < 3; ++ll)
        #pragma unroll
        for (int ka = 0; ka < 4; ++ka)
            #pragma unroll
            for (int jj = 0; jj < 4; ++jj) {
                const float* p = W_h + (size_t)(ll * 128 + 8 * kc + 2 * ka) * 128
                               + jb + (jj ^ kch);
                f2 v; v.x = p[0]; v.y = p[128];
                wgt[ll][ka][jj] = v;
            }

    // Input layer is register-direct: wave w covers row rw = w&3, cols
    // j2 = l + 64*(w>>2); writes go to the permuted slot rw ^ ((j2>>3)&3).
    // x-vector is wave-uniform in registers; the two y3 terms fold into
    // one staged weight.
    const int j2 = l + 64 * (w >> 2);
    const int waddr2 = haddr(j2, rw ^ ((j2 >> 3) & 3));
    float win[8];
    win[0] = W_in[0 * 128 + j2];                         // t
    win[1] = W_in[1 * 128 + j2];                         // y0
    win[2] = W_in[2 * 128 + j2];                         // y1
    win[3] = W_in[3 * 128 + j2];                         // y2
    win[4] = W_in[4 * 128 + j2] + W_in[7 * 128 + j2];    // y3 (+ glp1=y3)
    win[5] = W_in[5 * 128 + j2];                         // y4
    win[6] = W_in[6 * 128 + j2];                         // y5
    win[7] = W_in[8 * 128 + j2];                         // v
    const float bin = b_in[j2];

    float bh[3];
    #pragma unroll
    for (int ll = 0; ll < 3; ++ll) bh[ll] = b_h[ll * 128 + j_p];

    // output layer: XOR-permuted weights for a 3-bit reduce-scatter (s lands at l&7)
    const int s8 = l & 7;
    float wo0p[8], wo1p[8], bo[6];
    #pragma unroll
    for (int p = 0; p < 8; ++p) {
        const int q = p ^ s8;
        wo0p[p] = (q < 6) ? W_out[l * 6 + q] : 0.0f;
        wo1p[p] = (q < 6) ? W_out[(l + 64) * 6 + q] : 0.0f;
    }
    #pragma unroll
    for (int s = 0; s < 6; ++s) bo[s] = b_out[s];
    // h3 reads for row rw at columns l and l+64: permuted slot is
    // rw ^ ((l>>3)&3) for both (since ((l+64)>>3)&3 == (l>>3)&3).
    const int oaddrA = haddr(l, rw ^ ((l >> 3) & 3));
    const int oaddrB = oaddrA + 288;   // haddr(l+64, same slot)

    float y[6];
    #pragma unroll
    for (int s = 0; s < 6; ++s) y[s] = y0[row * 6 + s];

    if (w < 4 && l == 0) {
        #pragma unroll
        for (int s = 0; s < 6; ++s) out[(size_t)row * kT * 6 + s] = y[s];
    }

    const float* mrow = meal + (size_t)row * kT;
    const float* vrow = tvns + (size_t)row * kT;

    auto dyn = [&](float t, const float* yc, float m, float v, float* d) {
        // ---- input layer 9->128, register-direct. Prior hp0 readers
        // (layer ll=2) are ordered by the previous dyn's post-L3 barrier.
        {
            float s = bin + t * win[0];
            s += yc[0] * win[1] + yc[1] * win[2] + yc[2] * win[3];
            s += yc[3] * win[4] + yc[4] * win[5] + yc[5] * win[6];
            s += v * win[7];
            hp0[waddr2] = fast_tanh(s);
        }
        __syncthreads();

        // ---- 3 hidden layers 128->128
        #pragma unroll
        for (int ll = 0; ll < 3; ++ll) {
            const float* rb = (ll & 1) ? hp1 : hp0;
            float*       wb = (ll & 1) ? hp0 : hp1;

            // acc[jj][rho]: rho is the SLOT index (permuted row). The f4
            // loads deliver slots positionally, so the GEMM is unchanged.
            f2 acc[4][4];
            #pragma unroll
            for (int ka = 0; ka < 4; ++ka) {
                const int base = 36 * kc + 8 * ka;
                f4 q0 = *(const f4*)(rb + base);
                f4 q1 = *(const f4*)(rb + base + 4);
                f2 h0 = __builtin_shufflevector(q0, q0, 0, 1);
                f2 h1 = __builtin_shufflevector(q0, q0, 2, 3);
                f2 h2 = __builtin_shufflevector(q1, q1, 0, 1);
                f2 h3 = __builtin_shufflevector(q1, q1, 2, 3);
                #pragma unroll
                for (int jj = 0; jj < 4; ++jj) {
                    const f2 wv = wgt[ll][ka][jj];
                    if (ka == 0) {
                        acc[jj][0] = h0 * wv;
                        acc[jj][1] = h1 * wv;
                        acc[jj][2] = h2 * wv;
                        acc[jj][3] = h3 * wv;
                    } else {
                        acc[jj][0] = h0 * wv + acc[jj][0];
                        acc[jj][1] = h1 * wv + acc[jj][1];
                        acc[jj][2] = h2 * wv + acc[jj][2];
                        acc[jj][3] = h3 * wv + acc[jj][3];
                    }
                }
            }

            // horizontal add over k-parity; A indexed by o = (jj<<2)|rho,
            // value is column j = jb + (jj ^ kch), slot rho.
            float A[16];
            #pragma unroll
            for (int o = 0; o < 16; ++o)
                A[o] = acc[o >> 2][o & 3].x + acc[o >> 2][o & 3].y;

            // 4-stage reduce-scatter over the 16 kc lanes -- ALL UNIFORM:
            // jj stages via the column-XOR, r stages via the row-slot
            // permutation (lane kc keeps slot rho; partner kc^1's slot
            // rho^1 holds the same physical row, and the final surviving
            // slot is 0 for every lane).
            // stage kc-bit2 <-> jj-bit0 (uniform, swz xor4)
            float B[8];    // index (jj1<<2)|rho
            #pragma unroll
            for (int i = 0; i < 8; ++i)
                B[i] = A[(i & 3) | ((i >> 2) << 3)]
                     + swz<0x101F>(A[(i & 3) | ((i >> 2) << 3) | 4]);
            // stage kc-bit3 <-> jj-bit1 (uniform, ror8 = xor8 in row16)
            float C[4];    // index rho
            #pragma unroll
            for (int r = 0; r < 4; ++r)
                C[r] = B[r] + dpp_ror8(B[r + 4]);
            // stage kc-bit0 <-> slot-bit0 (uniform, fused dpp add)
            const float D0 = C[0] + dpp_xor1(C[1]);
            const float D1 = C[2] + dpp_xor1(C[3]);
            // stage kc-bit1 <-> slot-bit1 (uniform, fused dpp add)
            const float S = D0 + dpp_xor2(D1);

            wb[waddr] = fast_tanh(S + bh[ll]);
            __syncthreads();
        }

        // ---- output layer 128->6 for this wave's row; h3 lives in hp1.
        // Reduce-scatter s to lane s8 (uniform, XOR'd weights), all-reduce
        // the 8-lane groups, then readlane-broadcast p[0..5] as wave scalars.
        const float hA = hp1[oaddrA];
        const float hB = hp1[oaddrB];
        float P[8];
        #pragma unroll
        for (int p = 0; p < 8; ++p) P[p] = hA * wo0p[p] + hB * wo1p[p];
        float Q[4];
        #pragma unroll
        for (int i = 0; i < 4; ++i) Q[i] = P[2*i] + dpp_xor1(P[2*i+1]);
        const float R0 = Q[0] + dpp_xor2(Q[1]);
        const float R1 = Q[2] + dpp_xor2(Q[3]);
        float S = R0 + swz<0x101F>(R1);   // xor4
        S += dpp_ror8(S);                 // xor8
        S += swz<0x401F>(S);              // xor16
        S += __shfl_xor(S, 32);           // xor32

        const float p0 = read_lane(S, 0);
        const float p1 = read_lane(S, 1);
        const float p2 = read_lane(S, 2);
        const float p3 = read_lane(S, 3);
        const float p4 = read_lane(S, 4);
        const float p5 = read_lane(S, 5);

        const float G = yc[0], I = yc[1], N = yc[2], L = yc[3], GE = yc[4], F = yc[5];
        d[0] = -0.01f*I*G + 0.05f*GE                                    + p0 + bo[0];
        d[1] = (G/(100.0f+G))*(1.0f + 2.0f*L/(5.0f+L)) - 0.1f*I         + p1 + bo[1];
        d[2] = -0.05f*N                                                 + p2 + bo[2];
        d[3] = 0.05f*GE - 0.2f*L                                        + p3 + bo[3];
        d[4] = m - 0.05f*GE                                             + p4 + bo[4];
        d[5] = -0.01f*I*F                                               + p5 + bo[5];
    };

    for (int i = 0; i < kT - 1; ++i) {
        const float t0 = t_span[i], t1 = t_span[i + 1];
        const float dt = t1 - t0;
        const float m0 = mrow[i], m1 = mrow[i + 1];
        const float v0 = vrow[i], v1 = vrow[i + 1];
        const float tm = t0 + 0.5f * dt;
        const float mm = 0.5f * (m0 + m1), vm = 0.5f * (v0 + v1);

        float d[6], ksum[6], yc[6];

        dyn(t0, y, m0, v0, d);
        #pragma unroll
        for (int s = 0; s < 6; ++s) { ksum[s] = d[s]; yc[s] = y[s] + 0.5f * dt * d[s]; }
        dyn(tm, yc, mm, vm, d);
        #pragma unroll
        for (int s = 0; s < 6; ++s) { ksum[s] += 2.0f * d[s]; yc[s] = y[s] + 0.5f * dt * d[s]; }
        dyn(tm, yc, mm, vm, d);
        #pragma unroll
        for (int s = 0; s < 6; ++s) { ksum[s] += 2.0f * d[s]; yc[s] = y[s] + dt * d[s]; }
        dyn(t1, yc, m1, v1, d);
        #pragma unroll
        for (int s = 0; s < 6; ++s) {
            ksum[s] += d[s];
            y[s] += (dt * (1.0f / 6.0f)) * ksum[s];
        }

        if (w < 4 && l == 0) {
            #pragma unroll
            for (int s = 0; s < 6; ++s)
                out[((size_t)row * kT + (i + 1)) * 6 + s] = y[s];
        }
    }
}

} // namespace

extern "C" void kernel_launch(void* const* d_in, const int* in_sizes, int n_in,
                              void* d_out, int out_size, void* d_ws, size_t ws_size,
                              hipStream_t stream) {
    const float* y0     = (const float*)d_in[0];
    const float* t_span = (const float*)d_in[1];
    const float* meal   = (const float*)d_in[2];
    const float* tvns   = (const float*)d_in[3];
    const float* W_in   = (const float*)d_in[4];
    const float* b_in   = (const float*)d_in[5];
    const float* W_h    = (const float*)d_in[6];
    const float* b_h    = (const float*)d_in[7];
    const float* W_out  = (const float*)d_in[8];
    const float* b_out  = (const float*)d_in[9];
    float* out          = (float*)d_out;

    hipLaunchKernelGGL(hybrid_ode_kernel, dim3(256), dim3(512), 0, stream,
                       y0, t_span, meal, tvns,
                       W_in, b_in, W_h, b_h, W_out, b_out, out);
}

// Round 16
// 2206.445 us; speedup vs baseline: 3.6917x; 1.0327x over previous
//
#include <hip/hip_runtime.h>

namespace {

constexpr int kT = 256;

typedef float f2 __attribute__((ext_vector_type(2)));
typedef float f4 __attribute__((ext_vector_type(4)));

__device__ __forceinline__ float fast_tanh(float x) {
    float e = __expf(2.0f * x);
    return 1.0f - 2.0f * __builtin_amdgcn_rcpf(e + 1.0f);
}

__device__ __forceinline__ float dpp_xor1(float x) {
    return __builtin_bit_cast(float, __builtin_amdgcn_update_dpp(
        0, __builtin_bit_cast(int, x), 0xB1, 0xF, 0xF, true)); // quad [1,0,3,2]
}
__device__ __forceinline__ float dpp_xor2(float x) {
    return __builtin_bit_cast(float, __builtin_amdgcn_update_dpp(
        0, __builtin_bit_cast(int, x), 0x4E, 0xF, 0xF, true)); // quad [2,3,0,1]
}
__device__ __forceinline__ float dpp_ror8(float x) {           // lane ^ 8 within row16
    return __builtin_bit_cast(float, __builtin_amdgcn_update_dpp(
        0, __builtin_bit_cast(int, x), 0x128, 0xF, 0xF, true)); // row_ror:8
}
template <int PAT>
__device__ __forceinline__ float swz(float x) {
    return __builtin_bit_cast(float,
        __builtin_amdgcn_ds_swizzle(__builtin_bit_cast(int, x), PAT));
}
__device__ __forceinline__ float read_lane(float x, int lane) {
    return __builtin_bit_cast(float,
        __builtin_amdgcn_readlane(__builtin_bit_cast(int, x), lane));
}

// h storage: SLOT s of index j at float offset 8*(j>>1) + 4*(j>>3) + 2*s
// + (j&1). ROW-SLOT PERMUTATION: row r of index j is stored at slot
// s = r ^ ((j>>3)&3); readers of index k have kc = k>>3, so in slot space
// every lane's surviving reduce-scatter slot is slot 0 -> the r-keyed
// butterfly stages are uniform fused dpp adds. Bonus (measured r15): this
// permutation de-phases LDS access -> SQ_LDS_BANK_CONFLICT = 0.
//
// STRUCTURAL LEDGER (hard-won; r = round):
//  * 512-thread block = 8 waves = 2 waves/SIMD ALWAYS -> hard 128 VGPR cap.
//    THIS f2-k-parity core is the ONLY register-stable GEMM shape found
//    (112 VGPR, no spill). TERMINALLY DEAD families (all 128-pin + GB-scale
//    scratch FETCH): f4-quad weights/accs (r1/r2/r5), k-major row-fast
//    layout with ANY acc shape (r9/r10/r13). Mechanism: k-serial
//    accumulation chains force load/extract hoisting; transient pressure
//    at the cap evicts the 96-reg wgt array. k-parity packing gives two
//    independent FMA chains per jj -> no hoisting -> fits.
//  * Occupancy is NOT a lever: a 2nd block/CU never co-resides (r7).
//    Keep 256 blocks x 512 threads, 4 rows/block.
//  * Butterfly: ALL stages uniform (col-XOR r3 + row-slot perm r15).
//    With all stages uniform, adds are order-invariant (15 total) -- so
//    order by EXCHANGE TYPE: dpp stages (fused, free) first, the
//    ds_swizzle stage LAST at 2 elems: 8 swz/layer -> 1 (this round).
//  * Horizontal k-parity adds (48/dyn) are the accepted price of the
//    register-stable shape; removing them (k-major) costs 3.5x in spill.
//  * LDS index maps MUST be checked injective before landing (r12 lesson).
__device__ __forceinline__ int haddr(int j, int s) {
    return 8 * (j >> 1) + 4 * (j >> 3) + 2 * s + (j & 1);
}

__global__ __launch_bounds__(512, 1) void hybrid_ode_kernel(
    const float* __restrict__ y0,
    const float* __restrict__ t_span,
    const float* __restrict__ meal,
    const float* __restrict__ tvns,
    const float* __restrict__ W_in, const float* __restrict__ b_in,
    const float* __restrict__ W_h,  const float* __restrict__ b_h,
    const float* __restrict__ W_out,const float* __restrict__ b_out,
    float* __restrict__ out)
{
    const int tid = threadIdx.x;
    const int w   = tid >> 6;          // wave 0..7
    const int l   = tid & 63;
    const int jgl = l >> 4;            // 0..3 j-group within wave
    const int kc  = l & 15;            // k-chunk (8 k's)
    const int kch = kc >> 2;           // high 2 bits of kc (column-XOR key)
    const int jg  = w * 4 + jgl;       // 0..31
    const int jb  = jg * 4;            // thread's 4 j's: jb..jb+3 (XOR-permuted)
    const int rw  = w & 3;             // batch row this wave carries
    const int row = blockIdx.x * 4 + rw;

    // produced output slot after reduce-scatter: row r_p of column j_p,
    // stored at the permuted slot r_p ^ ((j_p>>3)&3).
    const int r_p = kc & 3;
    const int j_p = jb + kch;
    const int waddr = haddr(j_p, r_p ^ ((j_p >> 3) & 3));

    __shared__ __align__(16) float hp0[576];
    __shared__ __align__(16) float hp1[576];

    // ---- one-time weight staging into registers
    // wgt[ll][ka][jj] holds column j = jb + (jj ^ kch): the column-XOR
    // makes the jj butterfly stages uniform.
    f2 wgt[3][4][4];   // [layer][kpair kappa][jj]: k = 8kc+2*ka (+1)
    #pragma unroll
    for (int ll = 0; ll < 3; ++ll)
        #pragma unroll
        for (int ka = 0; ka < 4; ++ka)
            #pragma unroll
            for (int jj = 0; jj < 4; ++jj) {
                const float* p = W_h + (size_t)(ll * 128 + 8 * kc + 2 * ka) * 128
                               + jb + (jj ^ kch);
                f2 v; v.x = p[0]; v.y = p[128];
                wgt[ll][ka][jj] = v;
            }

    // Input layer is register-direct: wave w covers row rw = w&3, cols
    // j2 = l + 64*(w>>2); writes go to the permuted slot rw ^ ((j2>>3)&3).
    const int j2 = l + 64 * (w >> 2);
    const int waddr2 = haddr(j2, rw ^ ((j2 >> 3) & 3));
    float win[8];
    win[0] = W_in[0 * 128 + j2];                         // t
    win[1] = W_in[1 * 128 + j2];                         // y0
    win[2] = W_in[2 * 128 + j2];                         // y1
    win[3] = W_in[3 * 128 + j2];                         // y2
    win[4] = W_in[4 * 128 + j2] + W_in[7 * 128 + j2];    // y3 (+ glp1=y3)
    win[5] = W_in[5 * 128 + j2];                         // y4
    win[6] = W_in[6 * 128 + j2];                         // y5
    win[7] = W_in[8 * 128 + j2];                         // v
    const float bin = b_in[j2];

    float bh[3];
    #pragma unroll
    for (int ll = 0; ll < 3; ++ll) bh[ll] = b_h[ll * 128 + j_p];

    // output layer: XOR-permuted weights for a 3-bit reduce-scatter (s lands at l&7)
    const int s8 = l & 7;
    float wo0p[8], wo1p[8], bo[6];
    #pragma unroll
    for (int p = 0; p < 8; ++p) {
        const int q = p ^ s8;
        wo0p[p] = (q < 6) ? W_out[l * 6 + q] : 0.0f;
        wo1p[p] = (q < 6) ? W_out[(l + 64) * 6 + q] : 0.0f;
    }
    #pragma unroll
    for (int s = 0; s < 6; ++s) bo[s] = b_out[s];
    // h3 reads for row rw at columns l and l+64: permuted slot is
    // rw ^ ((l>>3)&3) for both (since ((l+64)>>3)&3 == (l>>3)&3).
    const int oaddrA = haddr(l, rw ^ ((l >> 3) & 3));
    const int oaddrB = oaddrA + 288;   // haddr(l+64, same slot)

    float y[6];
    #pragma unroll
    for (int s = 0; s < 6; ++s) y[s] = y0[row * 6 + s];

    if (w < 4 && l == 0) {
        #pragma unroll
        for (int s = 0; s < 6; ++s) out[(size_t)row * kT * 6 + s] = y[s];
    }

    const float* mrow = meal + (size_t)row * kT;
    const float* vrow = tvns + (size_t)row * kT;

    auto dyn = [&](float t, const float* yc, float m, float v, float* d) {
        // ---- input layer 9->128, register-direct. Prior hp0 readers
        // (layer ll=2) are ordered by the previous dyn's post-L3 barrier.
        {
            float s = bin + t * win[0];
            s += yc[0] * win[1] + yc[1] * win[2] + yc[2] * win[3];
            s += yc[3] * win[4] + yc[4] * win[5] + yc[5] * win[6];
            s += v * win[7];
            hp0[waddr2] = fast_tanh(s);
        }
        __syncthreads();

        // ---- 3 hidden layers 128->128
        #pragma unroll
        for (int ll = 0; ll < 3; ++ll) {
            const float* rb = (ll & 1) ? hp1 : hp0;
            float*       wb = (ll & 1) ? hp0 : hp1;

            // acc[jj][rho]: rho is the SLOT index (permuted row).
            f2 acc[4][4];
            #pragma unroll
            for (int ka = 0; ka < 4; ++ka) {
                const int base = 36 * kc + 8 * ka;
                f4 q0 = *(const f4*)(rb + base);
                f4 q1 = *(const f4*)(rb + base + 4);
                f2 h0 = __builtin_shufflevector(q0, q0, 0, 1);
                f2 h1 = __builtin_shufflevector(q0, q0, 2, 3);
                f2 h2 = __builtin_shufflevector(q1, q1, 0, 1);
                f2 h3 = __builtin_shufflevector(q1, q1, 2, 3);
                #pragma unroll
                for (int jj = 0; jj < 4; ++jj) {
                    const f2 wv = wgt[ll][ka][jj];
                    if (ka == 0) {
                        acc[jj][0] = h0 * wv;
                        acc[jj][1] = h1 * wv;
                        acc[jj][2] = h2 * wv;
                        acc[jj][3] = h3 * wv;
                    } else {
                        acc[jj][0] = h0 * wv + acc[jj][0];
                        acc[jj][1] = h1 * wv + acc[jj][1];
                        acc[jj][2] = h2 * wv + acc[jj][2];
                        acc[jj][3] = h3 * wv + acc[jj][3];
                    }
                }
            }

            // horizontal add over k-parity; A indexed by o = (jj<<2)|rho,
            // value is column j = jb + (jj ^ kch), slot rho.
            float A[16];
            #pragma unroll
            for (int o = 0; o < 16; ++o)
                A[o] = acc[o >> 2][o & 3].x + acc[o >> 2][o & 3].y;

            // 4-stage reduce-scatter over the 16 kc lanes -- all uniform;
            // dpp (fused) stages first, the lone ds_swizzle stage LAST at
            // 2 elems (8 swz/layer -> 1). Each stage contracts a disjoint
            // index bit, so contraction order commutes; survivor = jj=0,
            // slot=0 = (col j_p, row kc&3) as before.
            // stage kc-bit3 <-> jj-bit1 (dpp ror8) @16
            float B[8];    // index (jj0<<2)|rho
            #pragma unroll
            for (int i = 0; i < 8; ++i)
                B[i] = A[i] + dpp_ror8(A[i + 8]);
            // stage kc-bit0 <-> slot-bit0 (dpp xor1) @8: keep rho even
            float C[4];    // index (jj0<<1)|rho1
            #pragma unroll
            for (int i = 0; i < 4; ++i)
                C[i] = B[2 * i] + dpp_xor1(B[2 * i + 1]);
            // stage kc-bit1 <-> slot-bit1 (dpp xor2) @4: keep rho1=0
            const float D0 = C[0] + dpp_xor2(C[1]);   // jj0=0
            const float D1 = C[2] + dpp_xor2(C[3]);   // jj0=1
            // stage kc-bit2 <-> jj-bit0 (swz xor4) @2
            const float S = D0 + swz<0x101F>(D1);

            wb[waddr] = fast_tanh(S + bh[ll]);
            __syncthreads();
        }

        // ---- output layer 128->6 for this wave's row; h3 lives in hp1.
        // Reduce-scatter s to lane s8 (uniform, XOR'd weights), all-reduce
        // the 8-lane groups, then readlane-broadcast p[0..5] as wave scalars.
        const float hA = hp1[oaddrA];
        const float hB = hp1[oaddrB];
        float P[8];
        #pragma unroll
        for (int p = 0; p < 8; ++p) P[p] = hA * wo0p[p] + hB * wo1p[p];
        float Q[4];
        #pragma unroll
        for (int i = 0; i < 4; ++i) Q[i] = P[2*i] + dpp_xor1(P[2*i+1]);
        const float R0 = Q[0] + dpp_xor2(Q[1]);
        const float R1 = Q[2] + dpp_xor2(Q[3]);
        float S = R0 + swz<0x101F>(R1);   // xor4
        S += dpp_ror8(S);                 // xor8
        S += swz<0x401F>(S);              // xor16
        S += __shfl_xor(S, 32);           // xor32

        const float p0 = read_lane(S, 0);
        const float p1 = read_lane(S, 1);
        const float p2 = read_lane(S, 2);
        const float p3 = read_lane(S, 3);
        const float p4 = read_lane(S, 4);
        const float p5 = read_lane(S, 5);

        const float G = yc[0], I = yc[1], N = yc[2], L = yc[3], GE = yc[4], F = yc[5];
        d[0] = -0.01f*I*G + 0.05f*GE                                    + p0 + bo[0];
        d[1] = (G/(100.0f+G))*(1.0f + 2.0f*L/(5.0f+L)) - 0.1f*I         + p1 + bo[1];
        d[2] = -0.05f*N                                                 + p2 + bo[2];
        d[3] = 0.05f*GE - 0.2f*L                                        + p3 + bo[3];
        d[4] = m - 0.05f*GE                                             + p4 + bo[4];
        d[5] = -0.01f*I*F                                               + p5 + bo[5];
    };

    for (int i = 0; i < kT - 1; ++i) {
        const float t0 = t_span[i], t1 = t_span[i + 1];
        const float dt = t1 - t0;
        const float m0 = mrow[i], m1 = mrow[i + 1];
        const float v0 = vrow[i], v1 = vrow[i + 1];
        const float tm = t0 + 0.5f * dt;
        const float mm = 0.5f * (m0 + m1), vm = 0.5f * (v0 + v1);

        float d[6], ksum[6], yc[6];

        dyn(t0, y, m0, v0, d);
        #pragma unroll
        for (int s = 0; s < 6; ++s) { ksum[s] = d[s]; yc[s] = y[s] + 0.5f * dt * d[s]; }
        dyn(tm, yc, mm, vm, d);
        #pragma unroll
        for (int s = 0; s < 6; ++s) { ksum[s] += 2.0f * d[s]; yc[s] = y[s] + 0.5f * dt * d[s]; }
        dyn(tm, yc, mm, vm, d);
        #pragma unroll
        for (int s = 0; s < 6; ++s) { ksum[s] += 2.0f * d[s]; yc[s] = y[s] + dt * d[s]; }
        dyn(t1, yc, m1, v1, d);
        #pragma unroll
        for (int s = 0; s < 6; ++s) {
            ksum[s] += d[s];
            y[s] += (dt * (1.0f / 6.0f)) * ksum[s];
        }

        if (w < 4 && l == 0) {
            #pragma unroll
            for (int s = 0; s < 6; ++s)
                out[((size_t)row * kT + (i + 1)) * 6 + s] = y[s];
        }
    }
}

} // namespace

extern "C" void kernel_launch(void* const* d_in, const int* in_sizes, int n_in,
                              void* d_out, int out_size, void* d_ws, size_t ws_size,
                              hipStream_t stream) {
    const float* y0     = (const float*)d_in[0];
    const float* t_span = (const float*)d_in[1];
    const float* meal   = (const float*)d_in[2];
    const float* tvns   = (const float*)d_in[3];
    const float* W_in   = (const float*)d_in[4];
    const float* b_in   = (const float*)d_in[5];
    const float* W_h    = (const float*)d_in[6];
    const float* b_h    = (const float*)d_in[7];
    const float* W_out  = (const float*)d_in[8];
    const float* b_out  = (const float*)d_in[9];
    float* out          = (float*)d_out;

    hipLaunchKernelGGL(hybrid_ode_kernel, dim3(256), dim3(512), 0, stream,
                       y0, t_span, meal, tvns,
                       W_in, b_in, W_h, b_h, W_out, b_out, out);
}

// Round 17
// 2025.532 us; speedup vs baseline: 4.0214x; 1.0893x over previous
//
#include <hip/hip_runtime.h>

namespace {

constexpr int kT = 256;

typedef _Float16 h2 __attribute__((ext_vector_type(2)));
typedef unsigned int u32;
typedef u32 u32x4 __attribute__((ext_vector_type(4)));

__device__ __forceinline__ float fast_tanh(float x) {
    float e = __expf(2.0f * x);
    return 1.0f - 2.0f * __builtin_amdgcn_rcpf(e + 1.0f);
}

__device__ __forceinline__ float fdot2(u32 a, u32 b, float c) {
    return __builtin_amdgcn_fdot2(__builtin_bit_cast(h2, a),
                                  __builtin_bit_cast(h2, b), c, false);
}
__device__ __forceinline__ u32 pack_f16(float a, float b) {
    h2 h; h.x = (_Float16)a; h.y = (_Float16)b;
    return __builtin_bit_cast(u32, h);
}

__device__ __forceinline__ float dpp_xor1(float x) {
    return __builtin_bit_cast(float, __builtin_amdgcn_update_dpp(
        0, __builtin_bit_cast(int, x), 0xB1, 0xF, 0xF, true)); // quad [1,0,3,2]
}
__device__ __forceinline__ float dpp_xor2(float x) {
    return __builtin_bit_cast(float, __builtin_amdgcn_update_dpp(
        0, __builtin_bit_cast(int, x), 0x4E, 0xF, 0xF, true)); // quad [2,3,0,1]
}
__device__ __forceinline__ float dpp_ror8(float x) {           // lane ^ 8 within row16
    return __builtin_bit_cast(float, __builtin_amdgcn_update_dpp(
        0, __builtin_bit_cast(int, x), 0x128, 0xF, 0xF, true)); // row_ror:8
}
template <int PAT>
__device__ __forceinline__ float swz(float x) {
    return __builtin_bit_cast(float,
        __builtin_amdgcn_ds_swizzle(__builtin_bit_cast(int, x), PAT));
}
__device__ __forceinline__ float read_lane(float x, int lane) {
    return __builtin_bit_cast(float,
        __builtin_amdgcn_readlane(__builtin_bit_cast(int, x), lane));
}

// h storage (f16): 32-bit word W(j2, s) = 4*j2 + 4*(j2>>2) + s holds
// {h[2*j2][row], h[2*j2+1][row]} as 2xf16, where the ROW-SLOT PERMUTATION
// stores row r at slot s = r ^ ((j>>3)&3) (j>>3 == j2>>2 for both halves).
// Readers of k-pair k2 have kc = k>>3 = j2>>2, so slot s holds row
// s ^ (kc&3) -- every butterfly stage stays uniform (r15) and the final
// survivor is slot 0 = row kc&3. v_dot2_f32_f16 consumes the k-parity
// pair INSIDE the instruction with f32 accumulation -> the 16 horizontal
// adds/layer of the f32 core disappear. Injective: group g=j2>>2 occupies
// words 20g..20g+15; max 315 < 320. Reads: b128 at 20kc+4ka, 16B-aligned,
// banks 2-way max (free). Writes: ds_write_b16, distinct words <=2-way.
//
// STRUCTURAL LEDGER (hard-won; r = round):
//  * 512-thread block = 8 waves = 2 waves/SIMD ALWAYS -> hard 128 VGPR cap.
//    The f2-k-parity pairing is the ONLY register-stable GEMM shape found
//    (112 VGPR f32; this f16 version halves wgt to 48 regs). TERMINALLY
//    DEAD: f4-quad shapes (r1/r2/r5), k-major row-fast layouts (r9/r10/
//    r13) -- all spill wholesale (128-pin + GB-scale scratch FETCH).
//    Mechanism: k-serial accumulation chains force load hoisting past the
//    cap. k-parity packing keeps independent chains -> fits.
//  * Occupancy is NOT a lever: a 2nd block/CU never co-resides (r7).
//    Keep 256 blocks x 512 threads, 4 rows/block.
//  * Butterfly: ALL stages uniform (col-XOR r3 + row-slot perm r15);
//    dpp (fused) stages first, lone ds_swizzle last at 2 elems (r16).
//    SQ_LDS_BANK_CONFLICT = 0 since r15.
//  * LDS index maps MUST be checked injective before landing (r12 lesson).
//  * f16 accuracy pre-commitment: products are exact (f32 accumulate);
//    only input rounding (~5e-4 rel). If absmax > threshold -> revert to
//    the r16 f32 core and declare ceiling.
__device__ __forceinline__ int hwaddr(int j2, int s) {
    return 4 * j2 + 4 * (j2 >> 2) + s;
}

__global__ __launch_bounds__(512, 1) void hybrid_ode_kernel(
    const float* __restrict__ y0,
    const float* __restrict__ t_span,
    const float* __restrict__ meal,
    const float* __restrict__ tvns,
    const float* __restrict__ W_in, const float* __restrict__ b_in,
    const float* __restrict__ W_h,  const float* __restrict__ b_h,
    const float* __restrict__ W_out,const float* __restrict__ b_out,
    float* __restrict__ out)
{
    const int tid = threadIdx.x;
    const int w   = tid >> 6;          // wave 0..7
    const int l   = tid & 63;
    const int jgl = l >> 4;            // 0..3 j-group within wave
    const int kc  = l & 15;            // k-chunk (8 k's)
    const int kch = kc >> 2;           // high 2 bits of kc (column-XOR key)
    const int jg  = w * 4 + jgl;       // 0..31
    const int jb  = jg * 4;            // thread's 4 j's: jb..jb+3 (XOR-permuted)
    const int rw  = w & 3;             // batch row this wave carries
    const int row = blockIdx.x * 4 + rw;

    // produced output after reduce-scatter: row r_p of column j_p, written
    // as the (j_p&1) half of word W(j_p>>1, r_p ^ ((j_p>>3)&3)).
    const int r_p = kc & 3;
    const int j_p = jb + kch;
    const int whalf = 2 * hwaddr(j_p >> 1, r_p ^ ((j_p >> 3) & 3)) + (j_p & 1);

    __shared__ __align__(16) u32 hp0[320];
    __shared__ __align__(16) u32 hp1[320];

    // ---- one-time weight staging: packed 2xf16 per k-pair.
    // wgt[ll][ka][jj] = {W_h[2k][col], W_h[2k+1][col]}, k-pair 8kc+2ka,
    // col = jb + (jj ^ kch) (column-XOR keeps jj stages uniform).
    u32 wgt[3][4][4];
    #pragma unroll
    for (int ll = 0; ll < 3; ++ll)
        #pragma unroll
        for (int ka = 0; ka < 4; ++ka)
            #pragma unroll
            for (int jj = 0; jj < 4; ++jj) {
                const float* p = W_h + (size_t)(ll * 128 + 8 * kc + 2 * ka) * 128
                               + jb + (jj ^ kch);
                wgt[ll][ka][jj] = pack_f16(p[0], p[128]);
            }

    // Input layer register-direct: wave w covers row rw = w&3, cols
    // j2 = l + 64*(w>>2); f16 write to half (j2&1) of word
    // W(j2>>1, rw ^ ((j2>>3)&3)). x-vector is wave-uniform in registers;
    // the two y3 terms fold into one staged weight.
    const int j2 = l + 64 * (w >> 2);
    const int whalf2 = 2 * hwaddr(j2 >> 1, rw ^ ((j2 >> 3) & 3)) + (j2 & 1);
    float win[8];
    win[0] = W_in[0 * 128 + j2];                         // t
    win[1] = W_in[1 * 128 + j2];                         // y0
    win[2] = W_in[2 * 128 + j2];                         // y1
    win[3] = W_in[3 * 128 + j2];                         // y2
    win[4] = W_in[4 * 128 + j2] + W_in[7 * 128 + j2];    // y3 (+ glp1=y3)
    win[5] = W_in[5 * 128 + j2];                         // y4
    win[6] = W_in[6 * 128 + j2];                         // y5
    win[7] = W_in[8 * 128 + j2];                         // v
    const float bin = b_in[j2];

    float bh[3];
    #pragma unroll
    for (int ll = 0; ll < 3; ++ll) bh[ll] = b_h[ll * 128 + j_p];

    // output layer: XOR-permuted weights for a 3-bit reduce-scatter (s lands at l&7)
    const int s8 = l & 7;
    float wo0p[8], wo1p[8], bo[6];
    #pragma unroll
    for (int p = 0; p < 8; ++p) {
        const int q = p ^ s8;
        wo0p[p] = (q < 6) ? W_out[l * 6 + q] : 0.0f;
        wo1p[p] = (q < 6) ? W_out[(l + 64) * 6 + q] : 0.0f;
    }
    #pragma unroll
    for (int s = 0; s < 6; ++s) bo[s] = b_out[s];
    // h3 reads (f16) for row rw at columns l and l+64: same slot for both
    // (((l+64)>>3)&3 == (l>>3)&3); halfword index B = A + 2*160.
    const int oA = 2 * hwaddr(l >> 1, rw ^ ((l >> 3) & 3)) + (l & 1);
    const int oB = oA + 320;

    float y[6];
    #pragma unroll
    for (int s = 0; s < 6; ++s) y[s] = y0[row * 6 + s];

    if (w < 4 && l == 0) {
        #pragma unroll
        for (int s = 0; s < 6; ++s) out[(size_t)row * kT * 6 + s] = y[s];
    }

    const float* mrow = meal + (size_t)row * kT;
    const float* vrow = tvns + (size_t)row * kT;

    auto dyn = [&](float t, const float* yc, float m, float v, float* d) {
        // ---- input layer 9->128, register-direct. Prior hp0 readers
        // (layer ll=2) are ordered by the previous dyn's post-L3 barrier.
        {
            float s = bin + t * win[0];
            s += yc[0] * win[1] + yc[1] * win[2] + yc[2] * win[3];
            s += yc[3] * win[4] + yc[4] * win[5] + yc[5] * win[6];
            s += v * win[7];
            const float hv = fast_tanh(s);
            ((unsigned short*)hp0)[whalf2] =
                __builtin_bit_cast(unsigned short, (_Float16)hv);
        }
        __syncthreads();

        // ---- 3 hidden layers 128->128
        #pragma unroll
        for (int ll = 0; ll < 3; ++ll) {
            const u32* rb = (ll & 1) ? hp1 : hp0;
            u32*       wb = (ll & 1) ? hp0 : hp1;

            // 4x ds_read_b128: q[s] = packed h-pair (k2=4kc+ka, slot s).
            // acc[jj][s] f32; dot2 consumes the k-pair -> no horizontal add.
            const u32* hb = rb + 20 * kc;
            float acc[4][4];
            #pragma unroll
            for (int ka = 0; ka < 4; ++ka) {
                u32x4 q = *(const u32x4*)(hb + 4 * ka);
                #pragma unroll
                for (int jj = 0; jj < 4; ++jj) {
                    const u32 wv = wgt[ll][ka][jj];
                    if (ka == 0) {
                        acc[jj][0] = fdot2(q.x, wv, 0.0f);
                        acc[jj][1] = fdot2(q.y, wv, 0.0f);
                        acc[jj][2] = fdot2(q.z, wv, 0.0f);
                        acc[jj][3] = fdot2(q.w, wv, 0.0f);
                    } else {
                        acc[jj][0] = fdot2(q.x, wv, acc[jj][0]);
                        acc[jj][1] = fdot2(q.y, wv, acc[jj][1]);
                        acc[jj][2] = fdot2(q.z, wv, acc[jj][2]);
                        acc[jj][3] = fdot2(q.w, wv, acc[jj][3]);
                    }
                }
            }

            // 4-stage reduce-scatter over the 16 kc lanes -- all uniform;
            // dpp (fused) stages first, the lone ds_swizzle stage LAST at
            // 2 elems. A[(jj<<2)|s] = acc[jj][s]; survivor = jj=0, slot 0
            // = (col j_p, row kc&3).
            // stage kc-bit3 <-> jj-bit1 (dpp ror8) @16
            float B[8];    // index (jj0<<2)|s
            #pragma unroll
            for (int i = 0; i < 8; ++i)
                B[i] = acc[i >> 2][i & 3] + dpp_ror8(acc[(i >> 2) | 2][i & 3]);
            // stage kc-bit0 <-> slot-bit0 (dpp xor1) @8: keep s even
            float C[4];    // index (jj0<<1)|s1
            #pragma unroll
            for (int i = 0; i < 4; ++i)
                C[i] = B[2 * i] + dpp_xor1(B[2 * i + 1]);
            // stage kc-bit1 <-> slot-bit1 (dpp xor2) @4: keep s1=0
            const float D0 = C[0] + dpp_xor2(C[1]);   // jj0=0
            const float D1 = C[2] + dpp_xor2(C[3]);   // jj0=1
            // stage kc-bit2 <-> jj-bit0 (swz xor4) @2
            const float S = D0 + swz<0x101F>(D1);

            const float hv = fast_tanh(S + bh[ll]);
            ((unsigned short*)wb)[whalf] =
                __builtin_bit_cast(unsigned short, (_Float16)hv);
            __syncthreads();
        }

        // ---- output layer 128->6 for this wave's row; h3 (f16) in hp1.
        const _Float16* h3h = (const _Float16*)hp1;
        const float hA = (float)h3h[oA];
        const float hB = (float)h3h[oB];
        float P[8];
        #pragma unroll
        for (int p = 0; p < 8; ++p) P[p] = hA * wo0p[p] + hB * wo1p[p];
        float Q[4];
        #pragma unroll
        for (int i = 0; i < 4; ++i) Q[i] = P[2*i] + dpp_xor1(P[2*i+1]);
        const float R0 = Q[0] + dpp_xor2(Q[1]);
        const float R1 = Q[2] + dpp_xor2(Q[3]);
        float S = R0 + swz<0x101F>(R1);   // xor4
        S += dpp_ror8(S);                 // xor8
        S += swz<0x401F>(S);              // xor16
        S += __shfl_xor(S, 32);           // xor32

        const float p0 = read_lane(S, 0);
        const float p1 = read_lane(S, 1);
        const float p2 = read_lane(S, 2);
        const float p3 = read_lane(S, 3);
        const float p4 = read_lane(S, 4);
        const float p5 = read_lane(S, 5);

        const float G = yc[0], I = yc[1], N = yc[2], L = yc[3], GE = yc[4], F = yc[5];
        d[0] = -0.01f*I*G + 0.05f*GE                                    + p0 + bo[0];
        d[1] = (G/(100.0f+G))*(1.0f + 2.0f*L/(5.0f+L)) - 0.1f*I         + p1 + bo[1];
        d[2] = -0.05f*N                                                 + p2 + bo[2];
        d[3] = 0.05f*GE - 0.2f*L                                        + p3 + bo[3];
        d[4] = m - 0.05f*GE                                             + p4 + bo[4];
        d[5] = -0.01f*I*F                                               + p5 + bo[5];
    };

    for (int i = 0; i < kT - 1; ++i) {
        const float t0 = t_span[i], t1 = t_span[i + 1];
        const float dt = t1 - t0;
        const float m0 = mrow[i], m1 = mrow[i + 1];
        const float v0 = vrow[i], v1 = vrow[i + 1];
        const float tm = t0 + 0.5f * dt;
        const float mm = 0.5f * (m0 + m1), vm = 0.5f * (v0 + v1);

        float d[6], ksum[6], yc[6];

        dyn(t0, y, m0, v0, d);
        #pragma unroll
        for (int s = 0; s < 6; ++s) { ksum[s] = d[s]; yc[s] = y[s] + 0.5f * dt * d[s]; }
        dyn(tm, yc, mm, vm, d);
        #pragma unroll
        for (int s = 0; s < 6; ++s) { ksum[s] += 2.0f * d[s]; yc[s] = y[s] + 0.5f * dt * d[s]; }
        dyn(tm, yc, mm, vm, d);
        #pragma unroll
        for (int s = 0; s < 6; ++s) { ksum[s] += 2.0f * d[s]; yc[s] = y[s] + dt * d[s]; }
        dyn(t1, yc, m1, v1, d);
        #pragma unroll
        for (int s = 0; s < 6; ++s) {
            ksum[s] += d[s];
            y[s] += (dt * (1.0f / 6.0f)) * ksum[s];
        }

        if (w < 4 && l == 0) {
            #pragma unroll
            for (int s = 0; s < 6; ++s)
                out[((size_t)row * kT + (i + 1)) * 6 + s] = y[s];
        }
    }
}

} // namespace

extern "C" void kernel_launch(void* const* d_in, const int* in_sizes, int n_in,
                              void* d_out, int out_size, void* d_ws, size_t ws_size,
                              hipStream_t stream) {
    const float* y0     = (const float*)d_in[0];
    const float* t_span = (const float*)d_in[1];
    const float* meal   = (const float*)d_in[2];
    const float* tvns   = (const float*)d_in[3];
    const float* W_in   = (const float*)d_in[4];
    const float* b_in   = (const float*)d_in[5];
    const float* W_h    = (const float*)d_in[6];
    const float* b_h    = (const float*)d_in[7];
    const float* W_out  = (const float*)d_in[8];
    const float* b_out  = (const float*)d_in[9];
    float* out          = (float*)d_out;

    hipLaunchKernelGGL(hybrid_ode_kernel, dim3(256), dim3(512), 0, stream,
                       y0, t_span, meal, tvns,
                       W_in, b_in, W_h, b_h, W_out, b_out, out);
}

// Round 18
// 1965.682 us; speedup vs baseline: 4.1438x; 1.0304x over previous
//
#include <hip/hip_runtime.h>

namespace {

constexpr int kT = 256;

typedef _Float16 h2 __attribute__((ext_vector_type(2)));
typedef unsigned int u32;
typedef u32 u32x4 __attribute__((ext_vector_type(4)));

__device__ __forceinline__ float fast_tanh(float x) {
    float e = __expf(2.0f * x);
    return 1.0f - 2.0f * __builtin_amdgcn_rcpf(e + 1.0f);
}

__device__ __forceinline__ float fdot2(u32 a, u32 b, float c) {
    return __builtin_amdgcn_fdot2(__builtin_bit_cast(h2, a),
                                  __builtin_bit_cast(h2, b), c, false);
}
__device__ __forceinline__ u32 pack_f16(float a, float b) {
    h2 h; h.x = (_Float16)a; h.y = (_Float16)b;
    return __builtin_bit_cast(u32, h);
}

__device__ __forceinline__ float dpp_xor1(float x) {
    return __builtin_bit_cast(float, __builtin_amdgcn_update_dpp(
        0, __builtin_bit_cast(int, x), 0xB1, 0xF, 0xF, true)); // quad [1,0,3,2]
}
__device__ __forceinline__ float dpp_xor2(float x) {
    return __builtin_bit_cast(float, __builtin_amdgcn_update_dpp(
        0, __builtin_bit_cast(int, x), 0x4E, 0xF, 0xF, true)); // quad [2,3,0,1]
}
__device__ __forceinline__ float dpp_ror8(float x) {           // lane ^ 8 within row16
    return __builtin_bit_cast(float, __builtin_amdgcn_update_dpp(
        0, __builtin_bit_cast(int, x), 0x128, 0xF, 0xF, true)); // row_ror:8
}
template <int PAT>
__device__ __forceinline__ float swz(float x) {
    return __builtin_bit_cast(float,
        __builtin_amdgcn_ds_swizzle(__builtin_bit_cast(int, x), PAT));
}
__device__ __forceinline__ float read_lane(float x, int lane) {
    return __builtin_bit_cast(float,
        __builtin_amdgcn_readlane(__builtin_bit_cast(int, x), lane));
}

// h storage (f16): 32-bit word W(j2, s) = 4*j2 + 4*(j2>>2) + s holds
// {h[2*j2][row], h[2*j2+1][row]} as 2xf16, where the ROW-SLOT PERMUTATION
// stores row r at slot s = r ^ ((j>>3)&3) (j>>3 == j2>>2 for both halves).
// Readers of k-pair k2 have kc = k>>3 = j2>>2, so slot s holds row
// s ^ (kc&3) -- every butterfly stage stays uniform (r15) and the final
// survivor is slot 0 = row kc&3. v_dot2_f32_f16 consumes the k-parity
// pair INSIDE the instruction with f32 accumulation -> no horizontal adds.
// Injective; reads 16B-aligned 2-way max; SQ_LDS_BANK_CONFLICT = 0 (r15+).
//
// STRUCTURAL LEDGER (hard-won; r = round):
//  * 512-thread block = 8 waves = 2 waves/SIMD ALWAYS -> hard 128 VGPR cap.
//    The k-parity pairing is the ONLY register-stable GEMM shape found.
//    TERMINALLY DEAD: f4-quad shapes (r1/r2/r5), k-major row-fast layouts
//    (r9/r10/r13) -- all spill wholesale (128-pin + GB-scale scratch FETCH).
//  * Occupancy is NOT a lever: a 2nd block/CU never co-resides (r7).
//    Keep 256 blocks x 512 threads, 4 rows/block.
//  * Barrier count is MINIMAL at 4/dyn (input->L0->L1->L2->output chain;
//    output->next-input needs none). Residual ~28% VALU-idle ~= barrier
//    drain at pinned occupancy -- structural floor.
//  * Butterfly: ALL stages uniform (col-XOR r3 + row-slot perm r15);
//    dpp (fused) stages first, lone ds_swizzle last at 2 elems (r16).
//  * f16: products exact (f32 acc); input rounding ~5e-4 rel. absmax
//    0.125 vs threshold 0.345 (r17). W_out also f16-packed (this round).
//  * LDS index maps MUST be checked injective before landing (r12 lesson).
__device__ __forceinline__ int hwaddr(int j2, int s) {
    return 4 * j2 + 4 * (j2 >> 2) + s;
}

__global__ __launch_bounds__(512, 1) void hybrid_ode_kernel(
    const float* __restrict__ y0,
    const float* __restrict__ t_span,
    const float* __restrict__ meal,
    const float* __restrict__ tvns,
    const float* __restrict__ W_in, const float* __restrict__ b_in,
    const float* __restrict__ W_h,  const float* __restrict__ b_h,
    const float* __restrict__ W_out,const float* __restrict__ b_out,
    float* __restrict__ out)
{
    const int tid = threadIdx.x;
    const int w   = tid >> 6;          // wave 0..7
    const int l   = tid & 63;
    const int jgl = l >> 4;            // 0..3 j-group within wave
    const int kc  = l & 15;            // k-chunk (8 k's)
    const int kch = kc >> 2;           // high 2 bits of kc (column-XOR key)
    const int jg  = w * 4 + jgl;       // 0..31
    const int jb  = jg * 4;            // thread's 4 j's: jb..jb+3 (XOR-permuted)
    const int rw  = w & 3;             // batch row this wave carries
    const int row = blockIdx.x * 4 + rw;

    // produced output after reduce-scatter: row r_p of column j_p, written
    // as the (j_p&1) half of word W(j_p>>1, r_p ^ ((j_p>>3)&3)).
    const int r_p = kc & 3;
    const int j_p = jb + kch;
    const int whalf = 2 * hwaddr(j_p >> 1, r_p ^ ((j_p >> 3) & 3)) + (j_p & 1);

    __shared__ __align__(16) u32 hp0[320];
    __shared__ __align__(16) u32 hp1[320];

    // ---- one-time weight staging: packed 2xf16 per k-pair.
    // wgt[ll][ka][jj] = {W_h[2k][col], W_h[2k+1][col]}, k-pair 8kc+2ka,
    // col = jb + (jj ^ kch) (column-XOR keeps jj stages uniform).
    u32 wgt[3][4][4];
    #pragma unroll
    for (int ll = 0; ll < 3; ++ll)
        #pragma unroll
        for (int ka = 0; ka < 4; ++ka)
            #pragma unroll
            for (int jj = 0; jj < 4; ++jj) {
                const float* p = W_h + (size_t)(ll * 128 + 8 * kc + 2 * ka) * 128
                               + jb + (jj ^ kch);
                wgt[ll][ka][jj] = pack_f16(p[0], p[128]);
            }

    // Input layer register-direct: wave w covers row rw = w&3, cols
    // j2 = l + 64*(w>>2); f16 write to half (j2&1) of word
    // W(j2>>1, rw ^ ((j2>>3)&3)). The two y3 terms fold into one weight.
    const int j2 = l + 64 * (w >> 2);
    const int whalf2 = 2 * hwaddr(j2 >> 1, rw ^ ((j2 >> 3) & 3)) + (j2 & 1);
    float win[8];
    win[0] = W_in[0 * 128 + j2];                         // t
    win[1] = W_in[1 * 128 + j2];                         // y0
    win[2] = W_in[2 * 128 + j2];                         // y1
    win[3] = W_in[3 * 128 + j2];                         // y2
    win[4] = W_in[4 * 128 + j2] + W_in[7 * 128 + j2];    // y3 (+ glp1=y3)
    win[5] = W_in[5 * 128 + j2];                         // y4
    win[6] = W_in[6 * 128 + j2];                         // y5
    win[7] = W_in[8 * 128 + j2];                         // v
    const float bin = b_in[j2];

    float bh[3];
    #pragma unroll
    for (int ll = 0; ll < 3; ++ll) bh[ll] = b_h[ll * 128 + j_p];

    // output layer: XOR-permuted PACKED weights for a 3-bit reduce-scatter
    // (s lands at l&7). wop[p] = {W_out[l][q], W_out[l+64][q]}, q = p^s8.
    // b_out folded in pre-broadcast: bo_own added to S before readlanes.
    const int s8 = l & 7;
    u32 wop[8];
    #pragma unroll
    for (int p = 0; p < 8; ++p) {
        const int q = p ^ s8;
        wop[p] = (q < 6) ? pack_f16(W_out[l * 6 + q], W_out[(l + 64) * 6 + q])
                         : 0u;
    }
    const float bo_own = (s8 < 6) ? b_out[s8] : 0.0f;
    // h3 reads (f16) for row rw at columns l and l+64: same slot for both
    // (((l+64)>>3)&3 == (l>>3)&3); halfword index B = A + 2*160.
    const int oA = 2 * hwaddr(l >> 1, rw ^ ((l >> 3) & 3)) + (l & 1);
    const int oB = oA + 320;

    float y[6];
    #pragma unroll
    for (int s = 0; s < 6; ++s) y[s] = y0[row * 6 + s];

    if (w < 4 && l == 0) {
        #pragma unroll
        for (int s = 0; s < 6; ++s) out[(size_t)row * kT * 6 + s] = y[s];
    }

    const float* mrow = meal + (size_t)row * kT;
    const float* vrow = tvns + (size_t)row * kT;

    auto dyn = [&](float t, const float* yc, float m, float v, float* d) {
        // ---- input layer 9->128, register-direct. Prior hp0 readers
        // (layer ll=2) are ordered by the previous dyn's post-L3 barrier.
        {
            float s = bin + t * win[0];
            s += yc[0] * win[1] + yc[1] * win[2] + yc[2] * win[3];
            s += yc[3] * win[4] + yc[4] * win[5] + yc[5] * win[6];
            s += v * win[7];
            const float hv = fast_tanh(s);
            ((unsigned short*)hp0)[whalf2] =
                __builtin_bit_cast(unsigned short, (_Float16)hv);
        }
        __syncthreads();

        // ---- 3 hidden layers 128->128
        #pragma unroll
        for (int ll = 0; ll < 3; ++ll) {
            const u32* rb = (ll & 1) ? hp1 : hp0;
            u32*       wb = (ll & 1) ? hp0 : hp1;

            // 4x ds_read_b128: q[s] = packed h-pair (k2=4kc+ka, slot s).
            // acc[jj][s] f32; dot2 consumes the k-pair -> no horizontal add.
            const u32* hb = rb + 20 * kc;
            float acc[4][4];
            #pragma unroll
            for (int ka = 0; ka < 4; ++ka) {
                u32x4 q = *(const u32x4*)(hb + 4 * ka);
                #pragma unroll
                for (int jj = 0; jj < 4; ++jj) {
                    const u32 wv = wgt[ll][ka][jj];
                    if (ka == 0) {
                        acc[jj][0] = fdot2(q.x, wv, 0.0f);
                        acc[jj][1] = fdot2(q.y, wv, 0.0f);
                        acc[jj][2] = fdot2(q.z, wv, 0.0f);
                        acc[jj][3] = fdot2(q.w, wv, 0.0f);
                    } else {
                        acc[jj][0] = fdot2(q.x, wv, acc[jj][0]);
                        acc[jj][1] = fdot2(q.y, wv, acc[jj][1]);
                        acc[jj][2] = fdot2(q.z, wv, acc[jj][2]);
                        acc[jj][3] = fdot2(q.w, wv, acc[jj][3]);
                    }
                }
            }

            // 4-stage reduce-scatter over the 16 kc lanes -- all uniform;
            // dpp (fused) stages first, the lone ds_swizzle stage LAST at
            // 2 elems. A[(jj<<2)|s] = acc[jj][s]; survivor = jj=0, slot 0
            // = (col j_p, row kc&3).
            // stage kc-bit3 <-> jj-bit1 (dpp ror8) @16
            float B[8];    // index (jj0<<2)|s
            #pragma unroll
            for (int i = 0; i < 8; ++i)
                B[i] = acc[i >> 2][i & 3] + dpp_ror8(acc[(i >> 2) | 2][i & 3]);
            // stage kc-bit0 <-> slot-bit0 (dpp xor1) @8: keep s even
            float C[4];    // index (jj0<<1)|s1
            #pragma unroll
            for (int i = 0; i < 4; ++i)
                C[i] = B[2 * i] + dpp_xor1(B[2 * i + 1]);
            // stage kc-bit1 <-> slot-bit1 (dpp xor2) @4: keep s1=0
            const float D0 = C[0] + dpp_xor2(C[1]);   // jj0=0
            const float D1 = C[2] + dpp_xor2(C[3]);   // jj0=1
            // stage kc-bit2 <-> jj-bit0 (swz xor4) @2
            const float S = D0 + swz<0x101F>(D1);

            const float hv = fast_tanh(S + bh[ll]);
            ((unsigned short*)wb)[whalf] =
                __builtin_bit_cast(unsigned short, (_Float16)hv);
            __syncthreads();
        }

        // ---- output layer 128->6 for this wave's row; h3 (f16) in hp1.
        // Pack {h3[l], h3[l+64]} into one u32 and fdot2 against the packed
        // wop weights: 8 dot2 replace 16 FMA.
        const unsigned short* h3u = (const unsigned short*)hp1;
        const u32 hq = (u32)h3u[oA] | ((u32)h3u[oB] << 16);
        float P[8];
        #pragma unroll
        for (int p = 0; p < 8; ++p) P[p] = fdot2(hq, wop[p], 0.0f);
        float Q[4];
        #pragma unroll
        for (int i = 0; i < 4; ++i) Q[i] = P[2*i] + dpp_xor1(P[2*i+1]);
        const float R0 = Q[0] + dpp_xor2(Q[1]);
        const float R1 = Q[2] + dpp_xor2(Q[3]);
        float S = R0 + swz<0x101F>(R1);   // xor4
        S += dpp_ror8(S);                 // xor8
        S += swz<0x401F>(S);              // xor16
        S += __shfl_xor(S, 32);           // xor32
        S += bo_own;                      // fold b_out pre-broadcast

        const float p0 = read_lane(S, 0);
        const float p1 = read_lane(S, 1);
        const float p2 = read_lane(S, 2);
        const float p3 = read_lane(S, 3);
        const float p4 = read_lane(S, 4);
        const float p5 = read_lane(S, 5);

        const float G = yc[0], I = yc[1], N = yc[2], L = yc[3], GE = yc[4], F = yc[5];
        d[0] = -0.01f*I*G + 0.05f*GE                                    + p0;
        d[1] = (G/(100.0f+G))*(1.0f + 2.0f*L/(5.0f+L)) - 0.1f*I         + p1;
        d[2] = -0.05f*N                                                 + p2;
        d[3] = 0.05f*GE - 0.2f*L                                        + p3;
        d[4] = m - 0.05f*GE                                             + p4;
        d[5] = -0.01f*I*F                                               + p5;
    };

    for (int i = 0; i < kT - 1; ++i) {
        const float t0 = t_span[i], t1 = t_span[i + 1];
        const float dt = t1 - t0;
        const float m0 = mrow[i], m1 = mrow[i + 1];
        const float v0 = vrow[i], v1 = vrow[i + 1];
        const float tm = t0 + 0.5f * dt;
        const float mm = 0.5f * (m0 + m1), vm = 0.5f * (v0 + v1);

        float d[6], ksum[6], yc[6];

        dyn(t0, y, m0, v0, d);
        #pragma unroll
        for (int s = 0; s < 6; ++s) { ksum[s] = d[s]; yc[s] = y[s] + 0.5f * dt * d[s]; }
        dyn(tm, yc, mm, vm, d);
        #pragma unroll
        for (int s = 0; s < 6; ++s) { ksum[s] += 2.0f * d[s]; yc[s] = y[s] + 0.5f * dt * d[s]; }
        dyn(tm, yc, mm, vm, d);
        #pragma unroll
        for (int s = 0; s < 6; ++s) { ksum[s] += 2.0f * d[s]; yc[s] = y[s] + dt * d[s]; }
        dyn(t1, yc, m1, v1, d);
        #pragma unroll
        for (int s = 0; s < 6; ++s) {
            ksum[s] += d[s];
            y[s] += (dt * (1.0f / 6.0f)) * ksum[s];
        }

        if (w < 4 && l == 0) {
            #pragma unroll
            for (int s = 0; s < 6; ++s)
                out[((size_t)row * kT + (i + 1)) * 6 + s] = y[s];
        }
    }
}

} // namespace

extern "C" void kernel_launch(void* const* d_in, const int* in_sizes, int n_in,
                              void* d_out, int out_size, void* d_ws, size_t ws_size,
                              hipStream_t stream) {
    const float* y0     = (const float*)d_in[0];
    const float* t_span = (const float*)d_in[1];
    const float* meal   = (const float*)d_in[2];
    const float* tvns   = (const float*)d_in[3];
    const float* W_in   = (const float*)d_in[4];
    const float* b_in   = (const float*)d_in[5];
    const float* W_h    = (const float*)d_in[6];
    const float* b_h    = (const float*)d_in[7];
    const float* W_out  = (const float*)d_in[8];
    const float* b_out  = (const float*)d_in[9];
    float* out          = (float*)d_out;

    hipLaunchKernelGGL(hybrid_ode_kernel, dim3(256), dim3(512), 0, stream,
                       y0, t_span, meal, tvns,
                       W_in, b_in, W_h, b_h, W_out, b_out, out);
}

// Round 19
// 1509.000 us; speedup vs baseline: 5.3979x; 1.3026x over previous
//
#include <hip/hip_runtime.h>

namespace {

constexpr int kT = 256;

typedef _Float16 h2 __attribute__((ext_vector_type(2)));
typedef _Float16 f16x8 __attribute__((ext_vector_type(8)));
typedef float f32x4 __attribute__((ext_vector_type(4)));
typedef unsigned int u32;
typedef u32 u32x4 __attribute__((ext_vector_type(4)));

__device__ __forceinline__ float fast_tanh(float x) {
    float e = __expf(2.0f * x);
    return 1.0f - 2.0f * __builtin_amdgcn_rcpf(e + 1.0f);
}

__device__ __forceinline__ float fdot2(u32 a, u32 b, float c) {
    return __builtin_amdgcn_fdot2(__builtin_bit_cast(h2, a),
                                  __builtin_bit_cast(h2, b), c, false);
}
__device__ __forceinline__ u32 pack_f16(float a, float b) {
    h2 h; h.x = (_Float16)a; h.y = (_Float16)b;
    return __builtin_bit_cast(u32, h);
}

__device__ __forceinline__ float dpp_xor1(float x) {
    return __builtin_bit_cast(float, __builtin_amdgcn_update_dpp(
        0, __builtin_bit_cast(int, x), 0xB1, 0xF, 0xF, true)); // quad [1,0,3,2]
}
__device__ __forceinline__ float dpp_xor2(float x) {
    return __builtin_bit_cast(float, __builtin_amdgcn_update_dpp(
        0, __builtin_bit_cast(int, x), 0x4E, 0xF, 0xF, true)); // quad [2,3,0,1]
}
__device__ __forceinline__ float dpp_ror8(float x) {           // lane ^ 8 within row16
    return __builtin_bit_cast(float, __builtin_amdgcn_update_dpp(
        0, __builtin_bit_cast(int, x), 0x128, 0xF, 0xF, true)); // row_ror:8
}
template <int PAT>
__device__ __forceinline__ float swz(float x) {
    return __builtin_bit_cast(float,
        __builtin_amdgcn_ds_swizzle(__builtin_bit_cast(int, x), PAT));
}
__device__ __forceinline__ float read_lane(float x, int lane) {
    return __builtin_bit_cast(float,
        __builtin_amdgcn_readlane(__builtin_bit_cast(int, x), lane));
}

// MFMA hidden layers (this round): h stored as [16 rows][136 f16], row
// stride 68 u32 words (word j holds f16 cols 2j, 2j+1). Rows 0-3 real
// (the 4 batch rows), rows 4-15 zeroed once and never written -- M-pad
// garbage stays contained in unused C rows. Per layer, wave w computes
// N-tile cols 16w..16w+15 of the padded 16x128x128 GEMM as 4 K-step
// v_mfma_f32_16x16x32_f16 (f32 accumulate = same numerics as the r17
// fdot2 path). A-frag (assumed std layout: row=l&15, k=8*(l>>4)+e):
// one 16B-aligned ds_read_b128 per K-step at word (l&15)*68+4*(l>>4)+
// 16*ks -- bank-balanced (quad start 4*((m+g) mod 8), 8 lanes each).
// C (m89-verified): col=lane&15, row=(lane>>4)*4+reg -> lanes 0-15 hold
// all real rows; they apply bias+tanh and write 4 ds_write_b16 each.
// The dot2 GEMM + 4-stage butterfly reduce-scatter are GONE.
//
// STRUCTURAL LEDGER (hard-won; r = round):
//  * 512-thread block = 8 waves = 2 waves/SIMD ALWAYS -> hard 128 VGPR cap.
//    TERMINALLY DEAD: f4-quad f32 weight/acc shapes (r1/r2/r5), k-major
//    row-fast layouts (r9/r10/r13) -- spill wholesale (128-pin + GB-scale
//    scratch FETCH). WATCH: wgtB here is 12 quad-aligned f16x8 tuples;
//    spill signature -> revert to r18 (1965 us) and declare ceiling.
//  * Occupancy is NOT a lever: a 2nd block/CU never co-resides (r7).
//  * Barrier count minimal at 4/dyn (input->L0->L1->L2->output chain).
//  * Output layer: packed fdot2 + XOR-permuted reduce-scatter + folded
//    b_out (r17/r18). SQ_LDS_BANK_CONFLICT = 0 since r15.
//  * f16 numerics: products exact (f32 acc); absmax 0.125 vs thr 0.345.
//  * LDS index maps MUST be checked injective before landing (r12).
__global__ __launch_bounds__(512, 1) void hybrid_ode_kernel(
    const float* __restrict__ y0,
    const float* __restrict__ t_span,
    const float* __restrict__ meal,
    const float* __restrict__ tvns,
    const float* __restrict__ W_in, const float* __restrict__ b_in,
    const float* __restrict__ W_h,  const float* __restrict__ b_h,
    const float* __restrict__ W_out,const float* __restrict__ b_out,
    float* __restrict__ out)
{
    const int tid = threadIdx.x;
    const int w   = tid >> 6;          // wave 0..7
    const int l   = tid & 63;
    const int m16 = l & 15;            // A-row / C-col index within tile
    const int g4  = l >> 4;            // lane group 0..3
    const int rw  = w & 3;             // batch row this wave carries
    const int row = blockIdx.x * 4 + rw;
    const bool lanelo = (g4 == 0);     // lanes holding real C rows 0..3

    __shared__ __align__(16) u32 hp0[1088];   // 16 rows x 68 words
    __shared__ __align__(16) u32 hp1[1088];

    // zero-init both buffers (rows 4-15 stay zero forever)
    for (int idx = tid; idx < 1088; idx += 512) { hp0[idx] = 0u; hp1[idx] = 0u; }

    // ---- MFMA B-fragment staging: wgtB[ll][ks] = W_h[k][col] f16-packed,
    // col = 16w + m16, k = 32*ks + 8*g4 + e (e=0..7).
    f16x8 wgtB[3][4];
    const int colB = 16 * w + m16;
    #pragma unroll
    for (int ll = 0; ll < 3; ++ll)
        #pragma unroll
        for (int ks = 0; ks < 4; ++ks) {
            const int k0 = 32 * ks + 8 * g4;
            f16x8 bv;
            #pragma unroll
            for (int e = 0; e < 8; ++e)
                bv[e] = (_Float16)W_h[(size_t)(ll * 128 + k0 + e) * 128 + colB];
            wgtB[ll][ks] = bv;
        }
    float bhB[3];
    #pragma unroll
    for (int ll = 0; ll < 3; ++ll) bhB[ll] = b_h[ll * 128 + colB];

    // A-fragment read base (words): row m16, k-offset 8*g4
    const int abase = m16 * 68 + 4 * g4;
    // C write-back (lanes 0-15): col j = 16w + m16 -> word 8w + (m16>>1),
    // half m16&1, rows r=0..3 at +68r words.
    const int cwhalf = 2 * (8 * w + (m16 >> 1)) + (m16 & 1);

    // Input layer register-direct: wave w covers row rw, cols
    // j2 = l + 64*(w>>2); f16 write at word rw*68 + (j2>>1), half j2&1.
    const int j2 = l + 64 * (w >> 2);
    const int whalf2 = 2 * (rw * 68 + (j2 >> 1)) + (j2 & 1);
    float win[8];
    win[0] = W_in[0 * 128 + j2];                         // t
    win[1] = W_in[1 * 128 + j2];                         // y0
    win[2] = W_in[2 * 128 + j2];                         // y1
    win[3] = W_in[3 * 128 + j2];                         // y2
    win[4] = W_in[4 * 128 + j2] + W_in[7 * 128 + j2];    // y3 (+ glp1=y3)
    win[5] = W_in[5 * 128 + j2];                         // y4
    win[6] = W_in[6 * 128 + j2];                         // y5
    win[7] = W_in[8 * 128 + j2];                         // v
    const float bin = b_in[j2];

    // output layer: XOR-permuted PACKED weights (r18); b_out folded.
    const int s8 = l & 7;
    u32 wop[8];
    #pragma unroll
    for (int p = 0; p < 8; ++p) {
        const int q = p ^ s8;
        wop[p] = (q < 6) ? pack_f16(W_out[l * 6 + q], W_out[(l + 64) * 6 + q])
                         : 0u;
    }
    const float bo_own = (s8 < 6) ? b_out[s8] : 0.0f;
    // h3 reads (f16) for row rw at cols l and l+64 in the new layout
    const int oA = 2 * (rw * 68 + (l >> 1)) + (l & 1);
    const int oB = oA + 64;            // +32 words

    float y[6];
    #pragma unroll
    for (int s = 0; s < 6; ++s) y[s] = y0[row * 6 + s];

    if (w < 4 && l == 0) {
        #pragma unroll
        for (int s = 0; s < 6; ++s) out[(size_t)row * kT * 6 + s] = y[s];
    }

    const float* mrow = meal + (size_t)row * kT;
    const float* vrow = tvns + (size_t)row * kT;

    __syncthreads();   // zero-init visible to all

    auto dyn = [&](float t, const float* yc, float m, float v, float* d) {
        // ---- input layer 9->128, register-direct.
        {
            float s = bin + t * win[0];
            s += yc[0] * win[1] + yc[1] * win[2] + yc[2] * win[3];
            s += yc[3] * win[4] + yc[4] * win[5] + yc[5] * win[6];
            s += v * win[7];
            const float hv = fast_tanh(s);
            ((unsigned short*)hp0)[whalf2] =
                __builtin_bit_cast(unsigned short, (_Float16)hv);
        }
        __syncthreads();

        // ---- 3 hidden layers 128->128 via MFMA (padded M=16, 4 rows real)
        #pragma unroll
        for (int ll = 0; ll < 3; ++ll) {
            const u32* rb = (ll & 1) ? hp1 : hp0;
            u32*       wb = (ll & 1) ? hp0 : hp1;

            f32x4 cacc = {0.0f, 0.0f, 0.0f, 0.0f};
            #pragma unroll
            for (int ks = 0; ks < 4; ++ks) {
                const u32x4 aw = *(const u32x4*)(rb + abase + 16 * ks);
                cacc = __builtin_amdgcn_mfma_f32_16x16x32_f16(
                    __builtin_bit_cast(f16x8, aw), wgtB[ll][ks], cacc, 0, 0, 0);
            }
            if (lanelo) {
                #pragma unroll
                for (int r = 0; r < 4; ++r) {
                    const float hv = fast_tanh(cacc[r] + bhB[ll]);
                    ((unsigned short*)wb)[cwhalf + 136 * r] =
                        __builtin_bit_cast(unsigned short, (_Float16)hv);
                }
            }
            __syncthreads();
        }

        // ---- output layer 128->6 for this wave's row; h3 (f16) in hp1.
        const unsigned short* h3u = (const unsigned short*)hp1;
        const u32 hq = (u32)h3u[oA] | ((u32)h3u[oB] << 16);
        float P[8];
        #pragma unroll
        for (int p = 0; p < 8; ++p) P[p] = fdot2(hq, wop[p], 0.0f);
        float Q[4];
        #pragma unroll
        for (int i = 0; i < 4; ++i) Q[i] = P[2*i] + dpp_xor1(P[2*i+1]);
        const float R0 = Q[0] + dpp_xor2(Q[1]);
        const float R1 = Q[2] + dpp_xor2(Q[3]);
        float S = R0 + swz<0x101F>(R1);   // xor4
        S += dpp_ror8(S);                 // xor8
        S += swz<0x401F>(S);              // xor16
        S += __shfl_xor(S, 32);           // xor32
        S += bo_own;                      // fold b_out pre-broadcast

        const float p0 = read_lane(S, 0);
        const float p1 = read_lane(S, 1);
        const float p2 = read_lane(S, 2);
        const float p3 = read_lane(S, 3);
        const float p4 = read_lane(S, 4);
        const float p5 = read_lane(S, 5);

        const float G = yc[0], I = yc[1], N = yc[2], L = yc[3], GE = yc[4], F = yc[5];
        d[0] = -0.01f*I*G + 0.05f*GE                                    + p0;
        d[1] = (G/(100.0f+G))*(1.0f + 2.0f*L/(5.0f+L)) - 0.1f*I         + p1;
        d[2] = -0.05f*N                                                 + p2;
        d[3] = 0.05f*GE - 0.2f*L                                        + p3;
        d[4] = m - 0.05f*GE                                             + p4;
        d[5] = -0.01f*I*F                                               + p5;
    };

    for (int i = 0; i < kT - 1; ++i) {
        const float t0 = t_span[i], t1 = t_span[i + 1];
        const float dt = t1 - t0;
        const float m0 = mrow[i], m1 = mrow[i + 1];
        const float v0 = vrow[i], v1 = vrow[i + 1];
        const float tm = t0 + 0.5f * dt;
        const float mm = 0.5f * (m0 + m1), vm = 0.5f * (v0 + v1);

        float d[6], ksum[6], yc[6];

        dyn(t0, y, m0, v0, d);
        #pragma unroll
        for (int s = 0; s < 6; ++s) { ksum[s] = d[s]; yc[s] = y[s] + 0.5f * dt * d[s]; }
        dyn(tm, yc, mm, vm, d);
        #pragma unroll
        for (int s = 0; s < 6; ++s) { ksum[s] += 2.0f * d[s]; yc[s] = y[s] + 0.5f * dt * d[s]; }
        dyn(tm, yc, mm, vm, d);
        #pragma unroll
        for (int s = 0; s < 6; ++s) { ksum[s] += 2.0f * d[s]; yc[s] = y[s] + dt * d[s]; }
        dyn(t1, yc, m1, v1, d);
        #pragma unroll
        for (int s = 0; s < 6; ++s) {
            ksum[s] += d[s];
            y[s] += (dt * (1.0f / 6.0f)) * ksum[s];
        }

        if (w < 4 && l == 0) {
            #pragma unroll
            for (int s = 0; s < 6; ++s)
                out[((size_t)row * kT + (i + 1)) * 6 + s] = y[s];
        }
    }
}

} // namespace

extern "C" void kernel_launch(void* const* d_in, const int* in_sizes, int n_in,
                              void* d_out, int out_size, void* d_ws, size_t ws_size,
                              hipStream_t stream) {
    const float* y0     = (const float*)d_in[0];
    const float* t_span = (const float*)d_in[1];
    const float* meal   = (const float*)d_in[2];
    const float* tvns   = (const float*)d_in[3];
    const float* W_in   = (const float*)d_in[4];
    const float* b_in   = (const float*)d_in[5];
    const float* W_h    = (const float*)d_in[6];
    const float* b_h    = (const float*)d_in[7];
    const float* W_out  = (const float*)d_in[8];
    const float* b_out  = (const float*)d_in[9];
    float* out          = (float*)d_out;

    hipLaunchKernelGGL(hybrid_ode_kernel, dim3(256), dim3(512), 0, stream,
                       y0, t_span, meal, tvns,
                       W_in, b_in, W_h, b_h, W_out, b_out, out);
}